// Round 1
// baseline (318.532 us; speedup 1.0000x reference)
//
#include <hip/hip_runtime.h>
#include <hip/hip_bf16.h>

// ViT encoder block: B=8, N=1024, C=768, H=12, DH=64, FF=3072, fp32 in/out,
// bf16 MFMA compute internally.
#define BDIM 8
#define SEQ  1024
#define CH   768
#define NHD  12
#define DHD  64
#define FFD  3072
#define MR   (BDIM*SEQ)   // 8192 token rows

typedef __attribute__((ext_vector_type(8))) short bf16x8;
typedef __attribute__((ext_vector_type(4))) float f32x4;
typedef unsigned int   u32;
typedef unsigned short u16;

__device__ __forceinline__ u16 f2bfu(float x) {
  __hip_bfloat16 h = __float2bfloat16(x);
  return *reinterpret_cast<u16*>(&h);
}

__device__ __forceinline__ void glds16(const void* g, void* l) {
  __builtin_amdgcn_global_load_lds(
      (const __attribute__((address_space(1))) u32*)g,
      (__attribute__((address_space(3))) u32*)l, 16, 0, 0);
}

// ---------------------------------------------------------------- transpose
// W [K][Nc] fp32  ->  Wt [Nc][K] bf16   (so GEMM B-fragments read contiguous K)
__global__ __launch_bounds__(256) void k_transpose_bf16(
    const float* __restrict__ W, u16* __restrict__ Wt, int K, int Nc) {
  __shared__ float tile[32][33];
  int bx = blockIdx.x * 32;           // Nc dim
  int by = blockIdx.y * 32;           // K dim
  int tx = threadIdx.x & 31, ty = threadIdx.x >> 5;   // 32 x 8
#pragma unroll
  for (int j = 0; j < 32; j += 8)
    tile[ty + j][tx] = W[(size_t)(by + ty + j) * Nc + bx + tx];
  __syncthreads();
#pragma unroll
  for (int j = 0; j < 32; j += 8)
    Wt[(size_t)(bx + ty + j) * K + by + tx] = f2bfu(tile[tx][ty + j]);
}

// ---------------------------------------------------------------- layernorm
// one row (768) per wave; float4 loads; fp32 stats; bf16 out
__global__ __launch_bounds__(256) void k_layernorm_bf16(
    const float* __restrict__ src, const float* __restrict__ gamma,
    const float* __restrict__ beta, u16* __restrict__ dst) {
  int row  = blockIdx.x * 4 + (threadIdx.x >> 6);
  int lane = threadIdx.x & 63;
  const float4* p4 = (const float4*)(src + (size_t)row * CH);
  float4 v[3];
  float s = 0.f, s2 = 0.f;
#pragma unroll
  for (int k = 0; k < 3; k++) {
    v[k] = p4[lane + k * 64];
    s  += v[k].x + v[k].y + v[k].z + v[k].w;
    s2 += v[k].x * v[k].x + v[k].y * v[k].y + v[k].z * v[k].z + v[k].w * v[k].w;
  }
#pragma unroll
  for (int m = 1; m < 64; m <<= 1) {
    s  += __shfl_xor(s,  m, 64);
    s2 += __shfl_xor(s2, m, 64);
  }
  float mean = s * (1.f / CH);
  float var  = s2 * (1.f / CH) - mean * mean;
  float rs   = rsqrtf(var + 1e-5f);
  u16* drow = dst + (size_t)row * CH;
#pragma unroll
  for (int k = 0; k < 3; k++) {
    int col = lane * 4 + k * 256;
    float4 gq = ((const float4*)gamma)[lane + k * 64];
    float4 bq = ((const float4*)beta )[lane + k * 64];
    u32 lo = (u32)f2bfu((v[k].x - mean) * rs * gq.x + bq.x) |
             ((u32)f2bfu((v[k].y - mean) * rs * gq.y + bq.y) << 16);
    u32 hi = (u32)f2bfu((v[k].z - mean) * rs * gq.z + bq.z) |
             ((u32)f2bfu((v[k].w - mean) * rs * gq.w + bq.w) << 16);
    uint2 w; w.x = lo; w.y = hi;
    *(uint2*)(drow + col) = w;
  }
}

// ---------------------------------------------------------------- GEMM
// C[M][Nmat] = A[M][K](bf16) x Bt[Nmat][K](bf16)^T + bias, fused epilogues.
// m97 structure: 128x128 tile, BK=32, 4 waves (2x2 of 64x64), dbuf LDS,
// global_load_lds width-16 staging, 16 MFMA + 8 ds_read_b128 per wave/K-step.
#define GBM 128
#define GBN 128
#define GBK 32
enum { EPI_QKV = 0, EPI_RESID = 1, EPI_RELU = 2 };

template <int EPI>
__global__ __launch_bounds__(256, 2) void k_gemm(
    const u16* __restrict__ A, const u16* __restrict__ Bt,
    const float* __restrict__ bias, const float* __restrict__ resid,
    void* __restrict__ outp, int K, int Nmat) {
  __shared__ u16 As[2][GBM * GBK];
  __shared__ u16 Bs[2][GBN * GBK];
  int tid = threadIdx.x;
  int bm = blockIdx.x, bn = blockIdx.y;
  int lane = tid & 63, wid = tid >> 6;
  int wr = (wid >> 1) * 64, wc = (wid & 1) * 64;
  int lrow = lane & 15, g = lane >> 4;

  const u16* Abase = A + (size_t)(bm * GBM) * K;
  const u16* Bbase = Bt + (size_t)(bn * GBN) * K;
  int srow = tid >> 2;            // 0..63
  int scol = (tid & 3) * 8;       // 0,8,16,24

  auto stage = [&](int buf, int k0) {
#pragma unroll
    for (int r = 0; r < 2; r++) {
      glds16(Abase + (size_t)(srow + r * 64) * K + k0 + scol,
             &As[buf][(tid + r * 256) * 8]);
      glds16(Bbase + (size_t)(srow + r * 64) * K + k0 + scol,
             &Bs[buf][(tid + r * 256) * 8]);
    }
  };

  f32x4 acc[4][4];
#pragma unroll
  for (int m = 0; m < 4; m++)
#pragma unroll
    for (int n = 0; n < 4; n++) acc[m][n] = {0.f, 0.f, 0.f, 0.f};

  int nk = K / GBK;
  stage(0, 0);
  for (int kt = 0; kt < nk; ++kt) {
    int buf = kt & 1;
    __syncthreads();
    if (kt + 1 < nk) stage(buf ^ 1, (kt + 1) * GBK);
    bf16x8 af[4], bfr[4];
#pragma unroll
    for (int m = 0; m < 4; m++)
      af[m] = *(const bf16x8*)&As[buf][(wr + m * 16 + lrow) * GBK + g * 8];
#pragma unroll
    for (int n = 0; n < 4; n++)
      bfr[n] = *(const bf16x8*)&Bs[buf][(wc + n * 16 + lrow) * GBK + g * 8];
#pragma unroll
    for (int m = 0; m < 4; m++)
#pragma unroll
      for (int n = 0; n < 4; n++)
        acc[m][n] = __builtin_amdgcn_mfma_f32_16x16x32_bf16(af[m], bfr[n],
                                                            acc[m][n], 0, 0, 0);
  }

  // epilogue: D row = (lane>>4)*4 + r, col = lane&15 (m89-verified mapping)
#pragma unroll
  for (int m = 0; m < 4; m++) {
    int row0 = bm * GBM + wr + m * 16 + g * 4;
#pragma unroll
    for (int n = 0; n < 4; n++) {
      int col = bn * GBN + wc + n * 16 + lrow;
      float bval = bias[col];
#pragma unroll
      for (int r = 0; r < 4; r++) {
        int row = row0 + r;
        float val = acc[m][n][r] + bval;
        if constexpr (EPI == EPI_QKV) {
          // scatter to [B*H][N][DH]
          int bb = row >> 10, nn = row & (SEQ - 1);
          int h = col >> 6, d = col & 63;
          ((u16*)outp)[(((size_t)(bb * NHD + h)) * SEQ + nn) * DHD + d] =
              f2bfu(val);
        } else if constexpr (EPI == EPI_RESID) {
          size_t idx = (size_t)row * Nmat + col;
          ((float*)outp)[idx] = val + resid[idx];
        } else {  // RELU -> bf16 row-major
          size_t idx = (size_t)row * Nmat + col;
          ((u16*)outp)[idx] = f2bfu(val > 0.f ? val : 0.f);
        }
      }
    }
  }
}

// ---------------------------------------------------------------- attention
// flash-style; block = (128 q rows, one (b,h)); 4 waves x 32 q-rows.
// K tile [64kv][64d] and V tile transposed [64d][64kv] in LDS, rows padded to
// 72 elems (144B) -> conflict-free b128 fragment reads. Online softmax fp32.
__global__ __launch_bounds__(256, 2) void k_attn(
    const u16* __restrict__ Q, const u16* __restrict__ Kk,
    const u16* __restrict__ V, u16* __restrict__ Z) {
  __shared__ u16 Ks[64 * 72];
  __shared__ u16 Vs[64 * 72];        // Vs[d][kv]
  __shared__ u16 Ps[4][32 * 72];     // per-wave P tile
  int tid = threadIdx.x, lane = tid & 63, wid = tid >> 6;
  int lrow = lane & 15, g = lane >> 4;
  int qtile = blockIdx.x * 128;
  int bh = blockIdx.y;
  size_t base = (size_t)bh * SEQ * DHD;
  int bb = bh / NHD, hh = bh % NHD;
  int qrow0 = qtile + wid * 32;

  // Q fragments held in registers for the whole kernel
  bf16x8 qf[2][2];
#pragma unroll
  for (int m = 0; m < 2; m++)
#pragma unroll
    for (int ks = 0; ks < 2; ks++)
      qf[m][ks] = *(const bf16x8*)(Q + base +
                                   (size_t)(qrow0 + m * 16 + lrow) * DHD +
                                   ks * 32 + g * 8);

  f32x4 accO[2][4];
  float mrun[2][4], lrun[2][4];
#pragma unroll
  for (int m = 0; m < 2; m++) {
#pragma unroll
    for (int n = 0; n < 4; n++) accO[m][n] = {0.f, 0.f, 0.f, 0.f};
#pragma unroll
    for (int r = 0; r < 4; r++) { mrun[m][r] = -1e30f; lrun[m][r] = 0.f; }
  }

  for (int t = 0; t < 16; ++t) {
    int kv0 = t * 64;
    __syncthreads();  // previous tile fully consumed
    // stage K (row-major, pad 72) and V (transposed, pad 72) via registers
#pragma unroll
    for (int rr = 0; rr < 2; ++rr) {
      uint4 kval = *(const uint4*)(Kk + base + (size_t)(kv0 + (tid >> 2)) * DHD +
                                   (tid & 3) * 8 + rr * 32);
      *(uint4*)&Ks[(tid >> 2) * 72 + (tid & 3) * 8 + rr * 32] = kval;
      uint4 vval = *(const uint4*)(V + base + (size_t)(kv0 + (tid & 63)) * DHD +
                                   (tid >> 6) * 8 + rr * 32);
      const u16* vsrc = (const u16*)&vval;
#pragma unroll
      for (int j = 0; j < 8; j++)
        Vs[((tid >> 6) * 8 + rr * 32 + j) * 72 + (tid & 63)] = vsrc[j];
    }
    __syncthreads();

    // S = Q K^T  (scale 1/8 applied post-MFMA)
    bf16x8 kf[4][2];
#pragma unroll
    for (int n = 0; n < 4; n++)
#pragma unroll
      for (int ks = 0; ks < 2; ks++)
        kf[n][ks] = *(const bf16x8*)&Ks[(n * 16 + lrow) * 72 + ks * 32 + g * 8];
    f32x4 sacc[2][4];
#pragma unroll
    for (int m = 0; m < 2; m++)
#pragma unroll
      for (int n = 0; n < 4; n++) {
        sacc[m][n] = {0.f, 0.f, 0.f, 0.f};
#pragma unroll
        for (int ks = 0; ks < 2; ks++)
          sacc[m][n] = __builtin_amdgcn_mfma_f32_16x16x32_bf16(
              qf[m][ks], kf[n][ks], sacc[m][n], 0, 0, 0);
      }

    // online softmax per q-row (row = m*16 + g*4 + r, spread over 16 lanes)
#pragma unroll
    for (int m = 0; m < 2; m++)
#pragma unroll
      for (int r = 0; r < 4; r++) {
        float mx = fmaxf(fmaxf(sacc[m][0][r], sacc[m][1][r]),
                         fmaxf(sacc[m][2][r], sacc[m][3][r])) * 0.125f;
#pragma unroll
        for (int msk = 1; msk < 16; msk <<= 1)
          mx = fmaxf(mx, __shfl_xor(mx, msk, 64));
        float mnew = fmaxf(mrun[m][r], mx);
        float alpha = __expf(mrun[m][r] - mnew);
        float psum = 0.f;
#pragma unroll
        for (int n = 0; n < 4; n++) {
          float p = __expf(sacc[m][n][r] * 0.125f - mnew);
          sacc[m][n][r] = p;
          psum += p;
        }
#pragma unroll
        for (int msk = 1; msk < 16; msk <<= 1)
          psum += __shfl_xor(psum, msk, 64);
        lrun[m][r] = lrun[m][r] * alpha + psum;
        mrun[m][r] = mnew;
#pragma unroll
        for (int n = 0; n < 4; n++) accO[m][n][r] *= alpha;
      }

    // P (D-layout) -> LDS -> A-layout fragments
#pragma unroll
    for (int m = 0; m < 2; m++)
#pragma unroll
      for (int n = 0; n < 4; n++)
#pragma unroll
        for (int r = 0; r < 4; r++)
          Ps[wid][(m * 16 + g * 4 + r) * 72 + n * 16 + lrow] =
              f2bfu(sacc[m][n][r]);

    // O += P V
#pragma unroll
    for (int ks = 0; ks < 2; ks++) {
      bf16x8 vf[4], pf[2];
#pragma unroll
      for (int n = 0; n < 4; n++)
        vf[n] = *(const bf16x8*)&Vs[(n * 16 + lrow) * 72 + ks * 32 + g * 8];
#pragma unroll
      for (int m = 0; m < 2; m++)
        pf[m] = *(const bf16x8*)&Ps[wid][(m * 16 + lrow) * 72 + ks * 32 + g * 8];
#pragma unroll
      for (int m = 0; m < 2; m++)
#pragma unroll
        for (int n = 0; n < 4; n++)
          accO[m][n] = __builtin_amdgcn_mfma_f32_16x16x32_bf16(
              pf[m], vf[n], accO[m][n], 0, 0, 0);
    }
  }

  // normalize + write z in token-major [B][N][C] bf16
#pragma unroll
  for (int m = 0; m < 2; m++)
#pragma unroll
    for (int n = 0; n < 4; n++)
#pragma unroll
      for (int r = 0; r < 4; r++) {
        float o = accO[m][n][r] / lrun[m][r];
        int qrow = qrow0 + m * 16 + g * 4 + r;
        int d = n * 16 + lrow;
        Z[((size_t)(bb * SEQ + qrow)) * CH + hh * DHD + d] = f2bfu(o);
      }
}

// ---------------------------------------------------------------- launch
extern "C" void kernel_launch(void* const* d_in, const int* in_sizes, int n_in,
                              void* d_out, int out_size, void* d_ws,
                              size_t ws_size, hipStream_t stream) {
  (void)in_sizes; (void)n_in; (void)out_size; (void)ws_size;
  const float* x   = (const float*)d_in[0];
  const float* Wq  = (const float*)d_in[1];
  const float* bq  = (const float*)d_in[2];
  const float* Wk  = (const float*)d_in[3];
  const float* bk  = (const float*)d_in[4];
  const float* Wv  = (const float*)d_in[5];
  const float* bv  = (const float*)d_in[6];
  const float* Wo  = (const float*)d_in[7];
  const float* bo  = (const float*)d_in[8];
  const float* g1  = (const float*)d_in[9];
  const float* b1  = (const float*)d_in[10];
  const float* g2  = (const float*)d_in[11];
  const float* b2  = (const float*)d_in[12];
  const float* W1  = (const float*)d_in[13];
  const float* bf1 = (const float*)d_in[14];
  const float* W2  = (const float*)d_in[15];
  const float* bf2 = (const float*)d_in[16];

  // workspace layout (bf16 elems unless noted); total ~102.2 MB
  u16* wsu  = (u16*)d_ws;
  u16* wq_t = wsu;                               // [C][C]
  u16* wk_t = wq_t + (size_t)CH * CH;
  u16* wv_t = wk_t + (size_t)CH * CH;
  u16* wo_t = wv_t + (size_t)CH * CH;
  u16* w1_t = wo_t + (size_t)CH * CH;            // [FF][C]
  u16* w2_t = w1_t + (size_t)CH * FFD;           // [C][FF]
  u16* xn   = w2_t + (size_t)CH * FFD;           // [M][C], reused as bn
  u16* qb   = xn + (size_t)MR * CH;              // [B*H][N][DH]
  u16* kb   = qb + (size_t)MR * CH;
  u16* vb   = kb + (size_t)MR * CH;
  u16* zb   = vb + (size_t)MR * CH;              // [B][N][C]
  float* bres = (float*)(zb + (size_t)MR * CH);  // [M][C] fp32
  u16* hb   = qb;                                // reuse q/k/v/z region: [M][FF]

  dim3 blk(256);
  // weight transposes fp32 -> bf16 [N][K]
  k_transpose_bf16<<<dim3(24, 24), blk, 0, stream>>>(Wq, wq_t, CH, CH);
  k_transpose_bf16<<<dim3(24, 24), blk, 0, stream>>>(Wk, wk_t, CH, CH);
  k_transpose_bf16<<<dim3(24, 24), blk, 0, stream>>>(Wv, wv_t, CH, CH);
  k_transpose_bf16<<<dim3(24, 24), blk, 0, stream>>>(Wo, wo_t, CH, CH);
  k_transpose_bf16<<<dim3(96, 24), blk, 0, stream>>>(W1, w1_t, CH, FFD);
  k_transpose_bf16<<<dim3(24, 96), blk, 0, stream>>>(W2, w2_t, FFD, CH);

  // LN1
  k_layernorm_bf16<<<2048, blk, 0, stream>>>(x, g1, b1, xn);
  // QKV projections with head-scatter epilogue
  k_gemm<EPI_QKV><<<dim3(64, 6), blk, 0, stream>>>(xn, wq_t, bq, nullptr, qb, CH, CH);
  k_gemm<EPI_QKV><<<dim3(64, 6), blk, 0, stream>>>(xn, wk_t, bk, nullptr, kb, CH, CH);
  k_gemm<EPI_QKV><<<dim3(64, 6), blk, 0, stream>>>(xn, wv_t, bv, nullptr, vb, CH, CH);
  // attention
  k_attn<<<dim3(8, 96), blk, 0, stream>>>(qb, kb, vb, zb);
  // out-proj + residual (fp32)
  k_gemm<EPI_RESID><<<dim3(64, 6), blk, 0, stream>>>(zb, wo_t, bo, x, bres, CH, CH);
  // LN2
  k_layernorm_bf16<<<2048, blk, 0, stream>>>(bres, g2, b2, xn);
  // MLP
  k_gemm<EPI_RELU><<<dim3(64, 24), blk, 0, stream>>>(xn, w1_t, bf1, nullptr, hb, CH, FFD);
  k_gemm<EPI_RESID><<<dim3(64, 6), blk, 0, stream>>>(hb, w2_t, bf2, bres, (float*)d_out, FFD, CH);
}

// Round 2
// 308.633 us; speedup vs baseline: 1.0321x; 1.0321x over previous
//
#include <hip/hip_runtime.h>
#include <hip/hip_bf16.h>

// ViT encoder block: B=8, N=1024, C=768, H=12, DH=64, FF=3072, fp32 in/out,
// bf16 MFMA compute internally.
#define BDIM 8
#define SEQ  1024
#define CH   768
#define NHD  12
#define DHD  64
#define FFD  3072
#define MR   (BDIM*SEQ)   // 8192 token rows

typedef __attribute__((ext_vector_type(8))) short bf16x8;
typedef __attribute__((ext_vector_type(4))) float f32x4;
typedef unsigned int   u32;
typedef unsigned short u16;

__device__ __forceinline__ u16 f2bfu(float x) {
  __hip_bfloat16 h = __float2bfloat16(x);
  return *reinterpret_cast<u16*>(&h);
}

__device__ __forceinline__ void glds16(const void* g, void* l) {
  __builtin_amdgcn_global_load_lds(
      (const __attribute__((address_space(1))) u32*)g,
      (__attribute__((address_space(3))) u32*)l, 16, 0, 0);
}

// ---------------------------------------------------------------- transpose
// All 6 weights in one launch. W [K][Nc] fp32 -> Wt [Nc][K] bf16 in ws.
// Block ranges: [0,576)x4 for Wq/Wk/Wv/Wo (24x24 tiles), [2304,4608) W1
// (96x24), [4608,6912) W2 (24x96).
__global__ __launch_bounds__(256) void k_transpose_all(
    const float* __restrict__ Wq, const float* __restrict__ Wk,
    const float* __restrict__ Wv, const float* __restrict__ Wo,
    const float* __restrict__ W1, const float* __restrict__ W2,
    u16* __restrict__ ws) {
  __shared__ float tile[32][33];
  int b = blockIdx.x;
  int id, tb;
  if (b < 2304)      { id = b / 576; tb = b % 576; }
  else if (b < 4608) { id = 4;       tb = b - 2304; }
  else               { id = 5;       tb = b - 4608; }
  const float* src;
  u16* dst;
  int K, Nc;
  switch (id) {
    case 0: src = Wq; dst = ws;                      K = CH;  Nc = CH;  break;
    case 1: src = Wk; dst = ws + (size_t)CH*CH;      K = CH;  Nc = CH;  break;
    case 2: src = Wv; dst = ws + (size_t)2*CH*CH;    K = CH;  Nc = CH;  break;
    case 3: src = Wo; dst = ws + (size_t)3*CH*CH;    K = CH;  Nc = CH;  break;
    case 4: src = W1; dst = ws + (size_t)4*CH*CH;    K = CH;  Nc = FFD; break;
    default:src = W2; dst = ws + (size_t)4*CH*CH + (size_t)CH*FFD;
                                                     K = FFD; Nc = CH;  break;
  }
  int tilesx = Nc >> 5;
  int bx = (tb % tilesx) * 32;        // Nc dim
  int by = (tb / tilesx) * 32;        // K dim
  int tx = threadIdx.x & 31, ty = threadIdx.x >> 5;   // 32 x 8
#pragma unroll
  for (int j = 0; j < 32; j += 8)
    tile[ty + j][tx] = src[(size_t)(by + ty + j) * Nc + bx + tx];
  __syncthreads();
#pragma unroll
  for (int j = 0; j < 32; j += 8)
    dst[(size_t)(bx + ty + j) * K + by + tx] = f2bfu(tile[tx][ty + j]);
}

// ---------------------------------------------------------------- bias pack
// concat bq|bk|bv into a float[2304] buffer (placed at head of d_out, which
// is fully overwritten by the final GEMM afterwards).
__global__ __launch_bounds__(256) void k_pack_bias(
    const float* __restrict__ bq, const float* __restrict__ bk,
    const float* __restrict__ bv, float* __restrict__ dst) {
  int i = blockIdx.x * 256 + threadIdx.x;
  if (i < 3 * CH)
    dst[i] = i < CH ? bq[i] : (i < 2 * CH ? bk[i - CH] : bv[i - 2 * CH]);
}

// ---------------------------------------------------------------- layernorm
// one row (768) per wave; float4 loads; fp32 stats; bf16 out
__global__ __launch_bounds__(256) void k_layernorm_bf16(
    const float* __restrict__ src, const float* __restrict__ gamma,
    const float* __restrict__ beta, u16* __restrict__ dst) {
  int row  = blockIdx.x * 4 + (threadIdx.x >> 6);
  int lane = threadIdx.x & 63;
  const float4* p4 = (const float4*)(src + (size_t)row * CH);
  float4 v[3];
  float s = 0.f, s2 = 0.f;
#pragma unroll
  for (int k = 0; k < 3; k++) {
    v[k] = p4[lane + k * 64];
    s  += v[k].x + v[k].y + v[k].z + v[k].w;
    s2 += v[k].x * v[k].x + v[k].y * v[k].y + v[k].z * v[k].z + v[k].w * v[k].w;
  }
#pragma unroll
  for (int m = 1; m < 64; m <<= 1) {
    s  += __shfl_xor(s,  m, 64);
    s2 += __shfl_xor(s2, m, 64);
  }
  float mean = s * (1.f / CH);
  float var  = s2 * (1.f / CH) - mean * mean;
  float rs   = rsqrtf(var + 1e-5f);
  u16* drow = dst + (size_t)row * CH;
#pragma unroll
  for (int k = 0; k < 3; k++) {
    int col = lane * 4 + k * 256;
    float4 gq = ((const float4*)gamma)[lane + k * 64];
    float4 bq = ((const float4*)beta )[lane + k * 64];
    u32 lo = (u32)f2bfu((v[k].x - mean) * rs * gq.x + bq.x) |
             ((u32)f2bfu((v[k].y - mean) * rs * gq.y + bq.y) << 16);
    u32 hi = (u32)f2bfu((v[k].z - mean) * rs * gq.z + bq.z) |
             ((u32)f2bfu((v[k].w - mean) * rs * gq.w + bq.w) << 16);
    uint2 w; w.x = lo; w.y = hi;
    *(uint2*)(drow + col) = w;
  }
}

// ---------------------------------------------------------------- GEMM
// C[M][Nmat] = A[M][K](bf16) x Bt[Nmat][K](bf16)^T + bias, fused epilogues.
// m97 structure: 128x128 tile, BK=32, 4 waves (2x2 of 64x64), dbuf LDS,
// global_load_lds width-16 staging, 16 MFMA + 8 ds_read_b128 per wave/K-step.
#define GBM 128
#define GBN 128
#define GBK 32
enum { EPI_QKV = 0, EPI_RESID = 1, EPI_RELU = 2 };

template <int EPI>
__global__ __launch_bounds__(256, 2) void k_gemm(
    const u16* __restrict__ A, const u16* __restrict__ Bt,
    const float* __restrict__ bias, const float* __restrict__ resid,
    void* __restrict__ outp, int K, int Nmat) {
  __shared__ u16 As[2][GBM * GBK];
  __shared__ u16 Bs[2][GBN * GBK];
  int tid = threadIdx.x;
  int bm = blockIdx.x, bn = blockIdx.y;
  int lane = tid & 63, wid = tid >> 6;
  int wr = (wid >> 1) * 64, wc = (wid & 1) * 64;
  int lrow = lane & 15, g = lane >> 4;

  const u16* Abase = A + (size_t)(bm * GBM) * K;
  const u16* Bbase = Bt + (size_t)(bn * GBN) * K;
  int srow = tid >> 2;            // 0..63
  int scol = (tid & 3) * 8;       // 0,8,16,24

  auto stage = [&](int buf, int k0) {
#pragma unroll
    for (int r = 0; r < 2; r++) {
      glds16(Abase + (size_t)(srow + r * 64) * K + k0 + scol,
             &As[buf][(tid + r * 256) * 8]);
      glds16(Bbase + (size_t)(srow + r * 64) * K + k0 + scol,
             &Bs[buf][(tid + r * 256) * 8]);
    }
  };

  f32x4 acc[4][4];
#pragma unroll
  for (int m = 0; m < 4; m++)
#pragma unroll
    for (int n = 0; n < 4; n++) acc[m][n] = {0.f, 0.f, 0.f, 0.f};

  int nk = K / GBK;
  stage(0, 0);
  for (int kt = 0; kt < nk; ++kt) {
    int buf = kt & 1;
    __syncthreads();
    if (kt + 1 < nk) stage(buf ^ 1, (kt + 1) * GBK);
    bf16x8 af[4], bfr[4];
#pragma unroll
    for (int m = 0; m < 4; m++)
      af[m] = *(const bf16x8*)&As[buf][(wr + m * 16 + lrow) * GBK + g * 8];
#pragma unroll
    for (int n = 0; n < 4; n++)
      bfr[n] = *(const bf16x8*)&Bs[buf][(wc + n * 16 + lrow) * GBK + g * 8];
#pragma unroll
    for (int m = 0; m < 4; m++)
#pragma unroll
      for (int n = 0; n < 4; n++)
        acc[m][n] = __builtin_amdgcn_mfma_f32_16x16x32_bf16(af[m], bfr[n],
                                                            acc[m][n], 0, 0, 0);
  }

  // epilogue: D row = (lane>>4)*4 + r, col = lane&15 (m89-verified mapping)
#pragma unroll
  for (int m = 0; m < 4; m++) {
    int row0 = bm * GBM + wr + m * 16 + g * 4;
#pragma unroll
    for (int n = 0; n < 4; n++) {
      int col = bn * GBN + wc + n * 16 + lrow;
      float bval = bias[col];
#pragma unroll
      for (int r = 0; r < 4; r++) {
        int row = row0 + r;
        float val = acc[m][n][r] + bval;
        if constexpr (EPI == EPI_QKV) {
          // fused QKV: col in [0,2304); scatter to qb/kb/vb [B*H][N][DH]
          int sel = col / CH;
          int c = col - sel * CH;
          int bb = row >> 10, nn = row & (SEQ - 1);
          int h = c >> 6, d = c & 63;
          ((u16*)outp)[(size_t)sel * ((size_t)MR * CH) +
                       (((size_t)(bb * NHD + h)) * SEQ + nn) * DHD + d] =
              f2bfu(val);
        } else if constexpr (EPI == EPI_RESID) {
          size_t idx = (size_t)row * Nmat + col;
          ((float*)outp)[idx] = val + resid[idx];
        } else {  // RELU -> bf16 row-major
          size_t idx = (size_t)row * Nmat + col;
          ((u16*)outp)[idx] = f2bfu(val > 0.f ? val : 0.f);
        }
      }
    }
  }
}

// ---------------------------------------------------------------- attention
// flash-style; block = (64 q rows, one (b,h)); 4 waves x 16 q-rows.
// grid (16,96)=1536 blocks; LDS 27.6KB -> 5 blocks/CU resident.
// K tile [64kv][64d] and V tile transposed [64d][64kv] in LDS (pad 72).
// Async-stage split: next K/V tile prefetched into registers while current
// tile computes (T14). Online softmax fp32.
__global__ __launch_bounds__(256, 4) void k_attn(
    const u16* __restrict__ Q, const u16* __restrict__ Kk,
    const u16* __restrict__ V, u16* __restrict__ Z) {
  __shared__ u16 Ks[64 * 72];
  __shared__ u16 Vs[64 * 72];        // Vs[d][kv]
  __shared__ u16 Ps[4][16 * 72];     // per-wave P tile
  int tid = threadIdx.x, lane = tid & 63, wid = tid >> 6;
  int lrow = lane & 15, g = lane >> 4;
  int qtile = blockIdx.x * 64;
  int bh = blockIdx.y;
  size_t base = (size_t)bh * SEQ * DHD;
  int bb = bh / NHD, hh = bh % NHD;
  int qrow0 = qtile + wid * 16;

  // Q fragments held in registers for the whole kernel
  bf16x8 qf[2];
#pragma unroll
  for (int ks = 0; ks < 2; ks++)
    qf[ks] = *(const bf16x8*)(Q + base + (size_t)(qrow0 + lrow) * DHD +
                              ks * 32 + g * 8);

  f32x4 accO[4];
  float mrun[4], lrun[4];
#pragma unroll
  for (int n = 0; n < 4; n++) accO[n] = {0.f, 0.f, 0.f, 0.f};
#pragma unroll
  for (int r = 0; r < 4; r++) { mrun[r] = -1e30f; lrun[r] = 0.f; }

  // register staging buffers (async split)
  uint4 kreg[2], vreg[2];
  auto loadt = [&](int t) {
    int kv0 = t * 64;
#pragma unroll
    for (int rr = 0; rr < 2; ++rr) {
      kreg[rr] = *(const uint4*)(Kk + base + (size_t)(kv0 + (tid >> 2)) * DHD +
                                 (tid & 3) * 8 + rr * 32);
      vreg[rr] = *(const uint4*)(V + base + (size_t)(kv0 + (tid & 63)) * DHD +
                                 (tid >> 6) * 8 + rr * 32);
    }
  };

  loadt(0);
  for (int t = 0; t < 16; ++t) {
    __syncthreads();  // previous tile fully consumed
#pragma unroll
    for (int rr = 0; rr < 2; ++rr) {
      *(uint4*)&Ks[(tid >> 2) * 72 + (tid & 3) * 8 + rr * 32] = kreg[rr];
      const u16* vsrc = (const u16*)&vreg[rr];
#pragma unroll
      for (int j = 0; j < 8; j++)
        Vs[((tid >> 6) * 8 + rr * 32 + j) * 72 + (tid & 63)] = vsrc[j];
    }
    __syncthreads();
    if (t + 1 < 16) loadt(t + 1);   // HBM latency hides under compute below

    // S = Q K^T  (scale 1/8 applied post-MFMA)
    bf16x8 kf[4][2];
#pragma unroll
    for (int n = 0; n < 4; n++)
#pragma unroll
      for (int ks = 0; ks < 2; ks++)
        kf[n][ks] = *(const bf16x8*)&Ks[(n * 16 + lrow) * 72 + ks * 32 + g * 8];
    f32x4 sacc[4];
#pragma unroll
    for (int n = 0; n < 4; n++) {
      sacc[n] = {0.f, 0.f, 0.f, 0.f};
#pragma unroll
      for (int ks = 0; ks < 2; ks++)
        sacc[n] = __builtin_amdgcn_mfma_f32_16x16x32_bf16(
            qf[ks], kf[n][ks], sacc[n], 0, 0, 0);
    }

    // online softmax per q-row (row = g*4 + r, cols spread over lrow x n)
#pragma unroll
    for (int r = 0; r < 4; r++) {
      float mx = fmaxf(fmaxf(sacc[0][r], sacc[1][r]),
                       fmaxf(sacc[2][r], sacc[3][r])) * 0.125f;
#pragma unroll
      for (int msk = 1; msk < 16; msk <<= 1)
        mx = fmaxf(mx, __shfl_xor(mx, msk, 64));
      float mnew = fmaxf(mrun[r], mx);
      float alpha = __expf(mrun[r] - mnew);
      float psum = 0.f;
#pragma unroll
      for (int n = 0; n < 4; n++) {
        float p = __expf(sacc[n][r] * 0.125f - mnew);
        sacc[n][r] = p;
        psum += p;
      }
#pragma unroll
      for (int msk = 1; msk < 16; msk <<= 1)
        psum += __shfl_xor(psum, msk, 64);
      lrun[r] = lrun[r] * alpha + psum;
      mrun[r] = mnew;
#pragma unroll
      for (int n = 0; n < 4; n++) accO[n][r] *= alpha;
    }

    // P (D-layout) -> per-wave LDS tile -> A-layout fragments
#pragma unroll
    for (int n = 0; n < 4; n++)
#pragma unroll
      for (int r = 0; r < 4; r++)
        Ps[wid][(g * 4 + r) * 72 + n * 16 + lrow] = f2bfu(sacc[n][r]);

    // O += P V
#pragma unroll
    for (int ks = 0; ks < 2; ks++) {
      bf16x8 vf[4];
#pragma unroll
      for (int n = 0; n < 4; n++)
        vf[n] = *(const bf16x8*)&Vs[(n * 16 + lrow) * 72 + ks * 32 + g * 8];
      bf16x8 pf = *(const bf16x8*)&Ps[wid][lrow * 72 + ks * 32 + g * 8];
#pragma unroll
      for (int n = 0; n < 4; n++)
        accO[n] = __builtin_amdgcn_mfma_f32_16x16x32_bf16(
            pf, vf[n], accO[n], 0, 0, 0);
    }
  }

  // normalize + write z in token-major [B][N][C] bf16
#pragma unroll
  for (int r = 0; r < 4; r++) {
    float inv = 1.f / lrun[r];
    int qrow = qrow0 + g * 4 + r;
#pragma unroll
    for (int n = 0; n < 4; n++) {
      int d = n * 16 + lrow;
      Z[((size_t)(bb * SEQ + qrow)) * CH + hh * DHD + d] =
          f2bfu(accO[n][r] * inv);
    }
  }
}

// ---------------------------------------------------------------- launch
extern "C" void kernel_launch(void* const* d_in, const int* in_sizes, int n_in,
                              void* d_out, int out_size, void* d_ws,
                              size_t ws_size, hipStream_t stream) {
  (void)in_sizes; (void)n_in; (void)out_size; (void)ws_size;
  const float* x   = (const float*)d_in[0];
  const float* Wq  = (const float*)d_in[1];
  const float* bq  = (const float*)d_in[2];
  const float* Wk  = (const float*)d_in[3];
  const float* bk  = (const float*)d_in[4];
  const float* Wv  = (const float*)d_in[5];
  const float* bv  = (const float*)d_in[6];
  const float* Wo  = (const float*)d_in[7];
  const float* bo  = (const float*)d_in[8];
  const float* g1  = (const float*)d_in[9];
  const float* b1  = (const float*)d_in[10];
  const float* g2  = (const float*)d_in[11];
  const float* b2  = (const float*)d_in[12];
  const float* W1  = (const float*)d_in[13];
  const float* bf1 = (const float*)d_in[14];
  const float* W2  = (const float*)d_in[15];
  const float* bf2 = (const float*)d_in[16];

  // workspace layout (bf16 elems unless noted); total ~102.4 MB
  u16* wsu  = (u16*)d_ws;
  u16* wq_t = wsu;                               // [C][C] (wk,wv contiguous)
  u16* wo_t = wq_t + (size_t)3 * CH * CH;
  u16* w1_t = wo_t + (size_t)CH * CH;            // [FF][C]
  u16* w2_t = w1_t + (size_t)CH * FFD;           // [C][FF]
  u16* xn   = w2_t + (size_t)CH * FFD;           // [M][C], reused as bn
  u16* qb   = xn + (size_t)MR * CH;              // [B*H][N][DH]; kb,vb follow
  u16* zb   = qb + (size_t)3 * MR * CH;          // [B][N][C]
  float* bres = (float*)(zb + (size_t)MR * CH);  // [M][C] fp32
  u16* hb   = qb;                                // reuse q/k/v/z region: [M][FF]
  float* bqkv = (float*)d_out;                   // packed bias (overwritten later)

  dim3 blk(256);
  // all weight transposes fp32 -> bf16 [N][K] in one launch
  k_transpose_all<<<6912, blk, 0, stream>>>(Wq, Wk, Wv, Wo, W1, W2, wsu);
  k_pack_bias<<<9, blk, 0, stream>>>(bq, bk, bv, bqkv);

  // LN1
  k_layernorm_bf16<<<2048, blk, 0, stream>>>(x, g1, b1, xn);
  // fused QKV projection with head-scatter epilogue
  k_gemm<EPI_QKV><<<dim3(64, 18), blk, 0, stream>>>(xn, wq_t, bqkv, nullptr,
                                                    qb, CH, 3 * CH);
  // attention
  k_attn<<<dim3(16, 96), blk, 0, stream>>>(qb, qb + (size_t)MR * CH,
                                           qb + (size_t)2 * MR * CH, zb);
  // out-proj + residual (fp32)
  k_gemm<EPI_RESID><<<dim3(64, 6), blk, 0, stream>>>(zb, wo_t, bo, x, bres,
                                                     CH, CH);
  // LN2
  k_layernorm_bf16<<<2048, blk, 0, stream>>>(bres, g2, b2, xn);
  // MLP
  k_gemm<EPI_RELU><<<dim3(64, 24), blk, 0, stream>>>(xn, w1_t, bf1, nullptr,
                                                     hb, CH, FFD);
  k_gemm<EPI_RESID><<<dim3(64, 6), blk, 0, stream>>>(hb, w2_t, bf2, bres,
                                                     (float*)d_out, FFD, CH);
}

// Round 3
// 299.297 us; speedup vs baseline: 1.0643x; 1.0312x over previous
//
#include <hip/hip_runtime.h>
#include <hip/hip_bf16.h>

// ViT encoder block: B=8, N=1024, C=768, H=12, DH=64, FF=3072, fp32 in/out,
// bf16 MFMA compute internally.
#define BDIM 8
#define SEQ  1024
#define CH   768
#define NHD  12
#define DHD  64
#define FFD  3072
#define MR   (BDIM*SEQ)   // 8192 token rows

typedef __attribute__((ext_vector_type(8))) short bf16x8;
typedef __attribute__((ext_vector_type(4))) float f32x4;
typedef unsigned int   u32;
typedef unsigned short u16;

__device__ __forceinline__ u16 f2bfu(float x) {
  __hip_bfloat16 h = __float2bfloat16(x);
  return *reinterpret_cast<u16*>(&h);
}

__device__ __forceinline__ void glds16(const void* g, void* l) {
  __builtin_amdgcn_global_load_lds(
      (const __attribute__((address_space(1))) u32*)g,
      (__attribute__((address_space(3))) u32*)l, 16, 0, 0);
}

// ---------------------------------------------------------------- transpose
// All 6 weights in one launch. W [K][Nc] fp32 -> Wt [Nc][K] bf16 in ws.
__global__ __launch_bounds__(256) void k_transpose_all(
    const float* __restrict__ Wq, const float* __restrict__ Wk,
    const float* __restrict__ Wv, const float* __restrict__ Wo,
    const float* __restrict__ W1, const float* __restrict__ W2,
    u16* __restrict__ ws) {
  __shared__ float tile[32][33];
  int b = blockIdx.x;
  int id, tb;
  if (b < 2304)      { id = b / 576; tb = b % 576; }
  else if (b < 4608) { id = 4;       tb = b - 2304; }
  else               { id = 5;       tb = b - 4608; }
  const float* src;
  u16* dst;
  int K, Nc;
  switch (id) {
    case 0: src = Wq; dst = ws;                      K = CH;  Nc = CH;  break;
    case 1: src = Wk; dst = ws + (size_t)CH*CH;      K = CH;  Nc = CH;  break;
    case 2: src = Wv; dst = ws + (size_t)2*CH*CH;    K = CH;  Nc = CH;  break;
    case 3: src = Wo; dst = ws + (size_t)3*CH*CH;    K = CH;  Nc = CH;  break;
    case 4: src = W1; dst = ws + (size_t)4*CH*CH;    K = CH;  Nc = FFD; break;
    default:src = W2; dst = ws + (size_t)4*CH*CH + (size_t)CH*FFD;
                                                     K = FFD; Nc = CH;  break;
  }
  int tilesx = Nc >> 5;
  int bx = (tb % tilesx) * 32;        // Nc dim
  int by = (tb / tilesx) * 32;        // K dim
  int tx = threadIdx.x & 31, ty = threadIdx.x >> 5;   // 32 x 8
#pragma unroll
  for (int j = 0; j < 32; j += 8)
    tile[ty + j][tx] = src[(size_t)(by + ty + j) * Nc + bx + tx];
  __syncthreads();
#pragma unroll
  for (int j = 0; j < 32; j += 8)
    dst[(size_t)(bx + ty + j) * K + by + tx] = f2bfu(tile[tx][ty + j]);
}

// ---------------------------------------------------------------- bias pack
__global__ __launch_bounds__(256) void k_pack_bias(
    const float* __restrict__ bq, const float* __restrict__ bk,
    const float* __restrict__ bv, float* __restrict__ dst) {
  int i = blockIdx.x * 256 + threadIdx.x;
  if (i < 3 * CH)
    dst[i] = i < CH ? bq[i] : (i < 2 * CH ? bk[i - CH] : bv[i - 2 * CH]);
}

// ---------------------------------------------------------------- layernorm
__global__ __launch_bounds__(256) void k_layernorm_bf16(
    const float* __restrict__ src, const float* __restrict__ gamma,
    const float* __restrict__ beta, u16* __restrict__ dst) {
  int row  = blockIdx.x * 4 + (threadIdx.x >> 6);
  int lane = threadIdx.x & 63;
  const float4* p4 = (const float4*)(src + (size_t)row * CH);
  float4 v[3];
  float s = 0.f, s2 = 0.f;
#pragma unroll
  for (int k = 0; k < 3; k++) {
    v[k] = p4[lane + k * 64];
    s  += v[k].x + v[k].y + v[k].z + v[k].w;
    s2 += v[k].x * v[k].x + v[k].y * v[k].y + v[k].z * v[k].z + v[k].w * v[k].w;
  }
#pragma unroll
  for (int m = 1; m < 64; m <<= 1) {
    s  += __shfl_xor(s,  m, 64);
    s2 += __shfl_xor(s2, m, 64);
  }
  float mean = s * (1.f / CH);
  float var  = s2 * (1.f / CH) - mean * mean;
  float rs   = rsqrtf(var + 1e-5f);
  u16* drow = dst + (size_t)row * CH;
#pragma unroll
  for (int k = 0; k < 3; k++) {
    int col = lane * 4 + k * 256;
    float4 gq = ((const float4*)gamma)[lane + k * 64];
    float4 bq = ((const float4*)beta )[lane + k * 64];
    u32 lo = (u32)f2bfu((v[k].x - mean) * rs * gq.x + bq.x) |
             ((u32)f2bfu((v[k].y - mean) * rs * gq.y + bq.y) << 16);
    u32 hi = (u32)f2bfu((v[k].z - mean) * rs * gq.z + bq.z) |
             ((u32)f2bfu((v[k].w - mean) * rs * gq.w + bq.w) << 16);
    uint2 w; w.x = lo; w.y = hi;
    *(uint2*)(drow + col) = w;
  }
}

// ---------------------------------------------------------------- GEMM
// m97 structure: 128x128 tile, BK=32, 4 waves, dbuf LDS, global_load_lds.
#define GBM 128
#define GBN 128
#define GBK 32
enum { EPI_QKV = 0, EPI_RESID = 1, EPI_RELU = 2 };

template <int EPI>
__global__ __launch_bounds__(256, 2) void k_gemm(
    const u16* __restrict__ A, const u16* __restrict__ Bt,
    const float* __restrict__ bias, const float* __restrict__ resid,
    void* __restrict__ outp, int K, int Nmat) {
  __shared__ u16 As[2][GBM * GBK];
  __shared__ u16 Bs[2][GBN * GBK];
  int tid = threadIdx.x;
  int bm = blockIdx.x, bn = blockIdx.y;
  int lane = tid & 63, wid = tid >> 6;
  int wr = (wid >> 1) * 64, wc = (wid & 1) * 64;
  int lrow = lane & 15, g = lane >> 4;

  const u16* Abase = A + (size_t)(bm * GBM) * K;
  const u16* Bbase = Bt + (size_t)(bn * GBN) * K;
  int srow = tid >> 2;
  int scol = (tid & 3) * 8;

  auto stage = [&](int buf, int k0) {
#pragma unroll
    for (int r = 0; r < 2; r++) {
      glds16(Abase + (size_t)(srow + r * 64) * K + k0 + scol,
             &As[buf][(tid + r * 256) * 8]);
      glds16(Bbase + (size_t)(srow + r * 64) * K + k0 + scol,
             &Bs[buf][(tid + r * 256) * 8]);
    }
  };

  f32x4 acc[4][4];
#pragma unroll
  for (int m = 0; m < 4; m++)
#pragma unroll
    for (int n = 0; n < 4; n++) acc[m][n] = {0.f, 0.f, 0.f, 0.f};

  int nk = K / GBK;
  stage(0, 0);
  for (int kt = 0; kt < nk; ++kt) {
    int buf = kt & 1;
    __syncthreads();
    if (kt + 1 < nk) stage(buf ^ 1, (kt + 1) * GBK);
    bf16x8 af[4], bfr[4];
#pragma unroll
    for (int m = 0; m < 4; m++)
      af[m] = *(const bf16x8*)&As[buf][(wr + m * 16 + lrow) * GBK + g * 8];
#pragma unroll
    for (int n = 0; n < 4; n++)
      bfr[n] = *(const bf16x8*)&Bs[buf][(wc + n * 16 + lrow) * GBK + g * 8];
#pragma unroll
    for (int m = 0; m < 4; m++)
#pragma unroll
      for (int n = 0; n < 4; n++)
        acc[m][n] = __builtin_amdgcn_mfma_f32_16x16x32_bf16(af[m], bfr[n],
                                                            acc[m][n], 0, 0, 0);
  }

#pragma unroll
  for (int m = 0; m < 4; m++) {
    int row0 = bm * GBM + wr + m * 16 + g * 4;
#pragma unroll
    for (int n = 0; n < 4; n++) {
      int col = bn * GBN + wc + n * 16 + lrow;
      float bval = bias[col];
#pragma unroll
      for (int r = 0; r < 4; r++) {
        int row = row0 + r;
        float val = acc[m][n][r] + bval;
        if constexpr (EPI == EPI_QKV) {
          int sel = col / CH;
          int c = col - sel * CH;
          int bb = row >> 10, nn = row & (SEQ - 1);
          int h = c >> 6, d = c & 63;
          ((u16*)outp)[(size_t)sel * ((size_t)MR * CH) +
                       (((size_t)(bb * NHD + h)) * SEQ + nn) * DHD + d] =
              f2bfu(val);
        } else if constexpr (EPI == EPI_RESID) {
          size_t idx = (size_t)row * Nmat + col;
          ((float*)outp)[idx] = val + resid[idx];
        } else {
          size_t idx = (size_t)row * Nmat + col;
          ((u16*)outp)[idx] = f2bfu(val > 0.f ? val : 0.f);
        }
      }
    }
  }
}

// ---------------------------------------------------------------- attention
// flash-style, SWAPPED QK^T (S^T = K Q^T): each lane owns one q-row (q=lrow),
// softmax reduction = in-lane tree + 2 shfl_xor. Block = 64 q rows x one
// (b,h); 4 waves x 16 q. grid (16,96). LDS: K[64][72] + Vt[64][72] + per-wave
// u32 repack table (pad 9). T14 reg prefetch, T5 setprio.
__global__ __launch_bounds__(256, 2) void k_attn(
    const u16* __restrict__ Q, const u16* __restrict__ Kk,
    const u16* __restrict__ V, u16* __restrict__ Z) {
  __shared__ u16 Ks[64 * 72];
  __shared__ u16 Vs[64 * 72];        // Vs[d][kv]
  __shared__ u32 Psu[4][64 * 9];     // per-wave P repack: [lane][2n+hi]
  int tid = threadIdx.x, lane = tid & 63, wid = tid >> 6;
  int lrow = lane & 15, g = lane >> 4;
  int qtile = blockIdx.x * 64;
  int bh = blockIdx.y;
  size_t base = (size_t)bh * SEQ * DHD;
  int bb = bh / NHD, hh = bh % NHD;
  int qrow0 = qtile + wid * 16;

  // Q as B-operand fragments (col = q = lrow), held for the whole kernel
  bf16x8 qf[2];
#pragma unroll
  for (int ks = 0; ks < 2; ks++)
    qf[ks] = *(const bf16x8*)(Q + base + (size_t)(qrow0 + lrow) * DHD +
                              ks * 32 + g * 8);

  f32x4 accO[4];                 // O[q=g*4+r][d=n*16+lrow]
  float mrun = -1e30f, lrun = 0.f;  // stats for q = lrow (replicated over g)
#pragma unroll
  for (int n = 0; n < 4; n++) accO[n] = {0.f, 0.f, 0.f, 0.f};

  uint4 kreg[2], vreg[2];
  auto loadt = [&](int t) {
    int kv0 = t * 64;
#pragma unroll
    for (int rr = 0; rr < 2; ++rr) {
      kreg[rr] = *(const uint4*)(Kk + base + (size_t)(kv0 + (tid >> 2)) * DHD +
                                 (tid & 3) * 8 + rr * 32);
      vreg[rr] = *(const uint4*)(V + base + (size_t)(kv0 + (tid & 63)) * DHD +
                                 (tid >> 6) * 8 + rr * 32);
    }
  };

  loadt(0);
  for (int t = 0; t < 16; ++t) {
    __syncthreads();
#pragma unroll
    for (int rr = 0; rr < 2; ++rr) {
      *(uint4*)&Ks[(tid >> 2) * 72 + (tid & 3) * 8 + rr * 32] = kreg[rr];
      const u16* vsrc = (const u16*)&vreg[rr];
#pragma unroll
      for (int j = 0; j < 8; j++)
        Vs[((tid >> 6) * 8 + rr * 32 + j) * 72 + (tid & 63)] = vsrc[j];
    }
    __syncthreads();
    if (t + 1 < 16) loadt(t + 1);   // HBM latency hides under compute

    // S^T = K Q^T : sacc[n][r] = S[kv = n*16 + g*4 + r][q = lrow]
    f32x4 sacc[4];
    __builtin_amdgcn_s_setprio(1);
#pragma unroll
    for (int n = 0; n < 4; n++) {
      sacc[n] = {0.f, 0.f, 0.f, 0.f};
#pragma unroll
      for (int ks = 0; ks < 2; ks++) {
        bf16x8 kf = *(const bf16x8*)&Ks[(n * 16 + lrow) * 72 + ks * 32 + g * 8];
        sacc[n] = __builtin_amdgcn_mfma_f32_16x16x32_bf16(kf, qf[ks],
                                                          sacc[n], 0, 0, 0);
      }
    }
    __builtin_amdgcn_s_setprio(0);

    // online softmax for q = lrow: in-lane tree + 2 shfls
    float mx = fmaxf(fmaxf(fmaxf(sacc[0][0], sacc[0][1]),
                           fmaxf(sacc[0][2], sacc[0][3])),
                     fmaxf(fmaxf(sacc[1][0], sacc[1][1]),
                           fmaxf(sacc[1][2], sacc[1][3])));
    mx = fmaxf(mx, fmaxf(fmaxf(fmaxf(sacc[2][0], sacc[2][1]),
                               fmaxf(sacc[2][2], sacc[2][3])),
                         fmaxf(fmaxf(sacc[3][0], sacc[3][1]),
                               fmaxf(sacc[3][2], sacc[3][3]))));
    mx *= 0.125f;
    mx = fmaxf(mx, __shfl_xor(mx, 16, 64));
    mx = fmaxf(mx, __shfl_xor(mx, 32, 64));
    float mnew = fmaxf(mrun, mx);
    float alpha = __expf(mrun - mnew);
    float psum = 0.f;
#pragma unroll
    for (int n = 0; n < 4; n++)
#pragma unroll
      for (int r = 0; r < 4; r++) {
        float p = __expf(sacc[n][r] * 0.125f - mnew);
        sacc[n][r] = p;
        psum += p;
      }
    psum += __shfl_xor(psum, 16, 64);
    psum += __shfl_xor(psum, 32, 64);
    lrun = lrun * alpha + psum;
    mrun = mnew;

    // rescale O: row q' = g*4+r needs alpha of q'=lane (lane&48)|(g*4+r)
#pragma unroll
    for (int r = 0; r < 4; r++) {
      float ar = __shfl(alpha, (lane & 48) | (g * 4 + r), 64);
#pragma unroll
      for (int n = 0; n < 4; n++) accO[n][r] *= ar;
    }

    // pack P to bf16 pairs and publish to per-wave repack table (in-wave)
#pragma unroll
    for (int n = 0; n < 4; n++) {
      u32 lo = (u32)f2bfu(sacc[n][0]) | ((u32)f2bfu(sacc[n][1]) << 16);
      u32 hi = (u32)f2bfu(sacc[n][2]) | ((u32)f2bfu(sacc[n][3]) << 16);
      Psu[wid][lane * 9 + 2 * n]     = lo;
      Psu[wid][lane * 9 + 2 * n + 1] = hi;
    }

    // gather A-operand P fragments: pf[ks][j] = P[q=lrow][kv=ks*32+g*8+j]
    int laneA = lrow + ((g & 1) << 5);   // source g' = 2*(g&1)
    int laneB = laneA + 16;              // source g' = 2*(g&1)+1
    int nsel = g >> 1;
    __builtin_amdgcn_s_setprio(1);
#pragma unroll
    for (int ks = 0; ks < 2; ks++) {
      int nks = 2 * ks + nsel;
      union { bf16x8 v; u32 w[4]; } pk;
      pk.w[0] = Psu[wid][laneA * 9 + 2 * nks];
      pk.w[1] = Psu[wid][laneA * 9 + 2 * nks + 1];
      pk.w[2] = Psu[wid][laneB * 9 + 2 * nks];
      pk.w[3] = Psu[wid][laneB * 9 + 2 * nks + 1];
#pragma unroll
      for (int n = 0; n < 4; n++) {
        bf16x8 vf = *(const bf16x8*)&Vs[(n * 16 + lrow) * 72 + ks * 32 + g * 8];
        accO[n] = __builtin_amdgcn_mfma_f32_16x16x32_bf16(pk.v, vf,
                                                          accO[n], 0, 0, 0);
      }
    }
    __builtin_amdgcn_s_setprio(0);
  }

  // normalize + write z token-major [B][N][C] bf16; O row q'=g*4+r
#pragma unroll
  for (int r = 0; r < 4; r++) {
    float lr = __shfl(lrun, (lane & 48) | (g * 4 + r), 64);
    float inv = 1.f / lr;
    int qrow = qrow0 + g * 4 + r;
#pragma unroll
    for (int n = 0; n < 4; n++) {
      int d = n * 16 + lrow;
      Z[((size_t)(bb * SEQ + qrow)) * CH + hh * DHD + d] =
          f2bfu(accO[n][r] * inv);
    }
  }
}

// ---------------------------------------------------------------- launch
extern "C" void kernel_launch(void* const* d_in, const int* in_sizes, int n_in,
                              void* d_out, int out_size, void* d_ws,
                              size_t ws_size, hipStream_t stream) {
  (void)in_sizes; (void)n_in; (void)out_size; (void)ws_size;
  const float* x   = (const float*)d_in[0];
  const float* Wq  = (const float*)d_in[1];
  const float* bq  = (const float*)d_in[2];
  const float* Wk  = (const float*)d_in[3];
  const float* bk  = (const float*)d_in[4];
  const float* Wv  = (const float*)d_in[5];
  const float* bv  = (const float*)d_in[6];
  const float* Wo  = (const float*)d_in[7];
  const float* bo  = (const float*)d_in[8];
  const float* g1  = (const float*)d_in[9];
  const float* b1  = (const float*)d_in[10];
  const float* g2  = (const float*)d_in[11];
  const float* b2  = (const float*)d_in[12];
  const float* W1  = (const float*)d_in[13];
  const float* bf1 = (const float*)d_in[14];
  const float* W2  = (const float*)d_in[15];
  const float* bf2 = (const float*)d_in[16];

  u16* wsu  = (u16*)d_ws;
  u16* wq_t = wsu;                               // [3C][C] packed q,k,v
  u16* wo_t = wq_t + (size_t)3 * CH * CH;
  u16* w1_t = wo_t + (size_t)CH * CH;            // [FF][C]
  u16* w2_t = w1_t + (size_t)CH * FFD;           // [C][FF]
  u16* xn   = w2_t + (size_t)CH * FFD;           // [M][C]
  u16* qb   = xn + (size_t)MR * CH;              // [B*H][N][DH]; kb,vb follow
  u16* zb   = qb + (size_t)3 * MR * CH;          // [B][N][C]
  float* bres = (float*)(zb + (size_t)MR * CH);  // [M][C] fp32
  u16* hb   = qb;                                // reuse region: [M][FF]
  float* bqkv = (float*)d_out;                   // packed bias (overwritten)

  dim3 blk(256);
  k_transpose_all<<<6912, blk, 0, stream>>>(Wq, Wk, Wv, Wo, W1, W2, wsu);
  k_pack_bias<<<9, blk, 0, stream>>>(bq, bk, bv, bqkv);

  k_layernorm_bf16<<<2048, blk, 0, stream>>>(x, g1, b1, xn);
  k_gemm<EPI_QKV><<<dim3(64, 18), blk, 0, stream>>>(xn, wq_t, bqkv, nullptr,
                                                    qb, CH, 3 * CH);
  k_attn<<<dim3(16, 96), blk, 0, stream>>>(qb, qb + (size_t)MR * CH,
                                           qb + (size_t)2 * MR * CH, zb);
  k_gemm<EPI_RESID><<<dim3(64, 6), blk, 0, stream>>>(zb, wo_t, bo, x, bres,
                                                     CH, CH);
  k_layernorm_bf16<<<2048, blk, 0, stream>>>(bres, g2, b2, xn);
  k_gemm<EPI_RELU><<<dim3(64, 24), blk, 0, stream>>>(xn, w1_t, bf1, nullptr,
                                                     hb, CH, FFD);
  k_gemm<EPI_RESID><<<dim3(64, 6), blk, 0, stream>>>(hb, w2_t, bf2, bres,
                                                     (float*)d_out, FFD, CH);
}

// Round 4
// 275.495 us; speedup vs baseline: 1.1562x; 1.0864x over previous
//
#include <hip/hip_runtime.h>
#include <hip/hip_bf16.h>

// ViT encoder block: B=8, N=1024, C=768, H=12, DH=64, FF=3072, fp32 in/out,
// bf16 MFMA compute internally.
#define BDIM 8
#define SEQ  1024
#define CH   768
#define NHD  12
#define DHD  64
#define FFD  3072
#define MR   (BDIM*SEQ)   // 8192 token rows

typedef __attribute__((ext_vector_type(8))) short bf16x8;
typedef __attribute__((ext_vector_type(4))) float f32x4;
typedef unsigned int   u32;
typedef unsigned short u16;

__device__ __forceinline__ u16 f2bfu(float x) {
  __hip_bfloat16 h = __float2bfloat16(x);
  return *reinterpret_cast<u16*>(&h);
}

__device__ __forceinline__ void glds16(const void* g, void* l) {
  __builtin_amdgcn_global_load_lds(
      (const __attribute__((address_space(1))) u32*)g,
      (__attribute__((address_space(3))) u32*)l, 16, 0, 0);
}

// ---------------------------------------------------------------- transpose
// All 6 weights in one launch. W [K][Nc] fp32 -> Wt [Nc][K] bf16 in ws.
__global__ __launch_bounds__(256) void k_transpose_all(
    const float* __restrict__ Wq, const float* __restrict__ Wk,
    const float* __restrict__ Wv, const float* __restrict__ Wo,
    const float* __restrict__ W1, const float* __restrict__ W2,
    u16* __restrict__ ws) {
  __shared__ float tile[32][33];
  int b = blockIdx.x;
  int id, tb;
  if (b < 2304)      { id = b / 576; tb = b % 576; }
  else if (b < 4608) { id = 4;       tb = b - 2304; }
  else               { id = 5;       tb = b - 4608; }
  const float* src;
  u16* dst;
  int K, Nc;
  switch (id) {
    case 0: src = Wq; dst = ws;                      K = CH;  Nc = CH;  break;
    case 1: src = Wk; dst = ws + (size_t)CH*CH;      K = CH;  Nc = CH;  break;
    case 2: src = Wv; dst = ws + (size_t)2*CH*CH;    K = CH;  Nc = CH;  break;
    case 3: src = Wo; dst = ws + (size_t)3*CH*CH;    K = CH;  Nc = CH;  break;
    case 4: src = W1; dst = ws + (size_t)4*CH*CH;    K = CH;  Nc = FFD; break;
    default:src = W2; dst = ws + (size_t)4*CH*CH + (size_t)CH*FFD;
                                                     K = FFD; Nc = CH;  break;
  }
  int tilesx = Nc >> 5;
  int bx = (tb % tilesx) * 32;        // Nc dim
  int by = (tb / tilesx) * 32;        // K dim
  int tx = threadIdx.x & 31, ty = threadIdx.x >> 5;   // 32 x 8
#pragma unroll
  for (int j = 0; j < 32; j += 8)
    tile[ty + j][tx] = src[(size_t)(by + ty + j) * Nc + bx + tx];
  __syncthreads();
#pragma unroll
  for (int j = 0; j < 32; j += 8)
    dst[(size_t)(bx + ty + j) * K + by + tx] = f2bfu(tile[tx][ty + j]);
}

// ---------------------------------------------------------------- bias pack
__global__ __launch_bounds__(256) void k_pack_bias(
    const float* __restrict__ bq, const float* __restrict__ bk,
    const float* __restrict__ bv, float* __restrict__ dst) {
  int i = blockIdx.x * 256 + threadIdx.x;
  if (i < 3 * CH)
    dst[i] = i < CH ? bq[i] : (i < 2 * CH ? bk[i - CH] : bv[i - 2 * CH]);
}

// ---------------------------------------------------------------- layernorm
__global__ __launch_bounds__(256) void k_layernorm_bf16(
    const float* __restrict__ src, const float* __restrict__ gamma,
    const float* __restrict__ beta, u16* __restrict__ dst) {
  int row  = blockIdx.x * 4 + (threadIdx.x >> 6);
  int lane = threadIdx.x & 63;
  const float4* p4 = (const float4*)(src + (size_t)row * CH);
  float4 v[3];
  float s = 0.f, s2 = 0.f;
#pragma unroll
  for (int k = 0; k < 3; k++) {
    v[k] = p4[lane + k * 64];
    s  += v[k].x + v[k].y + v[k].z + v[k].w;
    s2 += v[k].x * v[k].x + v[k].y * v[k].y + v[k].z * v[k].z + v[k].w * v[k].w;
  }
#pragma unroll
  for (int m = 1; m < 64; m <<= 1) {
    s  += __shfl_xor(s,  m, 64);
    s2 += __shfl_xor(s2, m, 64);
  }
  float mean = s * (1.f / CH);
  float var  = s2 * (1.f / CH) - mean * mean;
  float rs   = rsqrtf(var + 1e-5f);
  u16* drow = dst + (size_t)row * CH;
#pragma unroll
  for (int k = 0; k < 3; k++) {
    int col = lane * 4 + k * 256;
    float4 gq = ((const float4*)gamma)[lane + k * 64];
    float4 bq = ((const float4*)beta )[lane + k * 64];
    u32 lo = (u32)f2bfu((v[k].x - mean) * rs * gq.x + bq.x) |
             ((u32)f2bfu((v[k].y - mean) * rs * gq.y + bq.y) << 16);
    u32 hi = (u32)f2bfu((v[k].z - mean) * rs * gq.z + bq.z) |
             ((u32)f2bfu((v[k].w - mean) * rs * gq.w + bq.w) << 16);
    uint2 w; w.x = lo; w.y = hi;
    *(uint2*)(drow + col) = w;
  }
}

// ---------------------------------------------------------------- GEMM
// m97 structure: 128x128 tile, BK=32, 4 waves, dbuf LDS, global_load_lds.
#define GBM 128
#define GBN 128
#define GBK 32
enum { EPI_QKV = 0, EPI_RESID = 1, EPI_RELU = 2 };

template <int EPI>
__global__ __launch_bounds__(256, 2) void k_gemm(
    const u16* __restrict__ A, const u16* __restrict__ Bt,
    const float* __restrict__ bias, const float* __restrict__ resid,
    void* __restrict__ outp, int K, int Nmat) {
  __shared__ u16 As[2][GBM * GBK];
  __shared__ u16 Bs[2][GBN * GBK];
  int tid = threadIdx.x;
  int bm = blockIdx.x, bn = blockIdx.y;
  int lane = tid & 63, wid = tid >> 6;
  int wr = (wid >> 1) * 64, wc = (wid & 1) * 64;
  int lrow = lane & 15, g = lane >> 4;

  const u16* Abase = A + (size_t)(bm * GBM) * K;
  const u16* Bbase = Bt + (size_t)(bn * GBN) * K;
  int srow = tid >> 2;
  int scol = (tid & 3) * 8;

  auto stage = [&](int buf, int k0) {
#pragma unroll
    for (int r = 0; r < 2; r++) {
      glds16(Abase + (size_t)(srow + r * 64) * K + k0 + scol,
             &As[buf][(tid + r * 256) * 8]);
      glds16(Bbase + (size_t)(srow + r * 64) * K + k0 + scol,
             &Bs[buf][(tid + r * 256) * 8]);
    }
  };

  f32x4 acc[4][4];
#pragma unroll
  for (int m = 0; m < 4; m++)
#pragma unroll
    for (int n = 0; n < 4; n++) acc[m][n] = {0.f, 0.f, 0.f, 0.f};

  int nk = K / GBK;
  stage(0, 0);
  for (int kt = 0; kt < nk; ++kt) {
    int buf = kt & 1;
    __syncthreads();
    if (kt + 1 < nk) stage(buf ^ 1, (kt + 1) * GBK);
    bf16x8 af[4], bfr[4];
#pragma unroll
    for (int m = 0; m < 4; m++)
      af[m] = *(const bf16x8*)&As[buf][(wr + m * 16 + lrow) * GBK + g * 8];
#pragma unroll
    for (int n = 0; n < 4; n++)
      bfr[n] = *(const bf16x8*)&Bs[buf][(wc + n * 16 + lrow) * GBK + g * 8];
#pragma unroll
    for (int m = 0; m < 4; m++)
#pragma unroll
      for (int n = 0; n < 4; n++)
        acc[m][n] = __builtin_amdgcn_mfma_f32_16x16x32_bf16(af[m], bfr[n],
                                                            acc[m][n], 0, 0, 0);
  }

#pragma unroll
  for (int m = 0; m < 4; m++) {
    int row0 = bm * GBM + wr + m * 16 + g * 4;
#pragma unroll
    for (int n = 0; n < 4; n++) {
      int col = bn * GBN + wc + n * 16 + lrow;
      float bval = bias[col];
#pragma unroll
      for (int r = 0; r < 4; r++) {
        int row = row0 + r;
        float val = acc[m][n][r] + bval;
        if constexpr (EPI == EPI_QKV) {
          int sel = col / CH;
          int c = col - sel * CH;
          int bb = row >> 10, nn = row & (SEQ - 1);
          int h = c >> 6, d = c & 63;
          ((u16*)outp)[(size_t)sel * ((size_t)MR * CH) +
                       (((size_t)(bb * NHD + h)) * SEQ + nn) * DHD + d] =
              f2bfu(val);
        } else if constexpr (EPI == EPI_RESID) {
          size_t idx = (size_t)row * Nmat + col;
          ((float*)outp)[idx] = val + resid[idx];
        } else {
          size_t idx = (size_t)row * Nmat + col;
          ((u16*)outp)[idx] = f2bfu(val > 0.f ? val : 0.f);
        }
      }
    }
  }
}

// ---------------------------------------------------------------- attention
// flash-style, SWAPPED QK^T (S^T = K Q^T): each lane owns one q-row (q=lrow),
// softmax reduction = in-lane tree + 2 shfl_xor. Block = 64 q rows x one
// (b,h); 4 waves x 16 q. grid 1536 blocks, bijective XCD swizzle so each XCD
// owns 12 complete (b,h) pairs (K/V L2-resident, 3MB/XCD).
// Staging: NAMED uint4 registers (k0,k1,v0,v1), straight-line conditional
// prefetch -- no register arrays (rule #20: arrays+lambda caused scratch
// demotion in rounds 2-3: VGPR 48, WRITE_SIZE 110MB).
__global__ __launch_bounds__(256, 2) void k_attn(
    const u16* __restrict__ Q, const u16* __restrict__ Kk,
    const u16* __restrict__ V, u16* __restrict__ Z) {
  __shared__ u16 Ks[64 * 72];
  __shared__ u16 Vs[64 * 72];        // Vs[d][kv]
  __shared__ u32 Psu[4][64 * 9];     // per-wave P repack: [lane][2n+hi]
  int tid = threadIdx.x, lane = tid & 63, wid = tid >> 6;
  int lrow = lane & 15, g = lane >> 4;
  // bijective XCD swizzle: 1536 blocks = 8 XCD x 192
  int id  = blockIdx.y * 16 + blockIdx.x;
  int nid = (id & 7) * 192 + (id >> 3);
  int qtile = (nid & 15) * 64;
  int bh = nid >> 4;
  size_t base = (size_t)bh * SEQ * DHD;
  int bb = bh / NHD, hh = bh % NHD;
  int qrow0 = qtile + wid * 16;

  // Q as B-operand fragments (col = q = lrow), held for the whole kernel
  bf16x8 qf[2];
#pragma unroll
  for (int ks = 0; ks < 2; ks++)
    qf[ks] = *(const bf16x8*)(Q + base + (size_t)(qrow0 + lrow) * DHD +
                              ks * 32 + g * 8);

  f32x4 accO[4];                    // O[q=g*4+r][d=n*16+lrow]
  float mrun = -1e30f, lrun = 0.f;  // stats for q = lrow (replicated over g)
#pragma unroll
  for (int n = 0; n < 4; n++) accO[n] = {0.f, 0.f, 0.f, 0.f};

  // named staging registers (no arrays!)
  uint4 k0, k1, v0, v1;
  const u16* kp = Kk + base + (size_t)(tid >> 2) * DHD + (tid & 3) * 8;
  const u16* vp = V + base + (size_t)(tid & 63) * DHD + (tid >> 6) * 8;
  k0 = *(const uint4*)(kp);
  k1 = *(const uint4*)(kp + 32);
  v0 = *(const uint4*)(vp);
  v1 = *(const uint4*)(vp + 32);

  for (int t = 0; t < 16; ++t) {
    __syncthreads();   // previous tile fully consumed
    // write staged regs -> LDS
    *(uint4*)&Ks[(tid >> 2) * 72 + (tid & 3) * 8]      = k0;
    *(uint4*)&Ks[(tid >> 2) * 72 + (tid & 3) * 8 + 32] = k1;
    {
      union { uint4 q; u16 h[8]; } uv;
      uv.q = v0;
#pragma unroll
      for (int j = 0; j < 8; j++)
        Vs[((tid >> 6) * 8 + j) * 72 + (tid & 63)] = uv.h[j];
      uv.q = v1;
#pragma unroll
      for (int j = 0; j < 8; j++)
        Vs[((tid >> 6) * 8 + 32 + j) * 72 + (tid & 63)] = uv.h[j];
    }
    __syncthreads();
    if (t + 1 < 16) {   // prefetch next tile; latency hides under compute
      size_t off = (size_t)(t + 1) * 64 * DHD;
      k0 = *(const uint4*)(kp + off);
      k1 = *(const uint4*)(kp + off + 32);
      v0 = *(const uint4*)(vp + off);
      v1 = *(const uint4*)(vp + off + 32);
    }

    // S^T = K Q^T : sacc[n][r] = S[kv = n*16 + g*4 + r][q = lrow]
    f32x4 sacc[4];
    __builtin_amdgcn_s_setprio(1);
#pragma unroll
    for (int n = 0; n < 4; n++) {
      sacc[n] = {0.f, 0.f, 0.f, 0.f};
#pragma unroll
      for (int ks = 0; ks < 2; ks++) {
        bf16x8 kf = *(const bf16x8*)&Ks[(n * 16 + lrow) * 72 + ks * 32 + g * 8];
        sacc[n] = __builtin_amdgcn_mfma_f32_16x16x32_bf16(kf, qf[ks],
                                                          sacc[n], 0, 0, 0);
      }
    }
    __builtin_amdgcn_s_setprio(0);

    // online softmax for q = lrow: in-lane tree + 2 shfls
    float mx = fmaxf(fmaxf(fmaxf(sacc[0][0], sacc[0][1]),
                           fmaxf(sacc[0][2], sacc[0][3])),
                     fmaxf(fmaxf(sacc[1][0], sacc[1][1]),
                           fmaxf(sacc[1][2], sacc[1][3])));
    mx = fmaxf(mx, fmaxf(fmaxf(fmaxf(sacc[2][0], sacc[2][1]),
                               fmaxf(sacc[2][2], sacc[2][3])),
                         fmaxf(fmaxf(sacc[3][0], sacc[3][1]),
                               fmaxf(sacc[3][2], sacc[3][3]))));
    mx *= 0.125f;
    mx = fmaxf(mx, __shfl_xor(mx, 16, 64));
    mx = fmaxf(mx, __shfl_xor(mx, 32, 64));
    float mnew = fmaxf(mrun, mx);
    float alpha = __expf(mrun - mnew);
    float psum = 0.f;
#pragma unroll
    for (int n = 0; n < 4; n++)
#pragma unroll
      for (int r = 0; r < 4; r++) {
        float p = __expf(sacc[n][r] * 0.125f - mnew);
        sacc[n][r] = p;
        psum += p;
      }
    psum += __shfl_xor(psum, 16, 64);
    psum += __shfl_xor(psum, 32, 64);
    lrun = lrun * alpha + psum;
    mrun = mnew;

    // rescale O: row q' = g*4+r needs alpha of lane (lane&48)|(g*4+r)
#pragma unroll
    for (int r = 0; r < 4; r++) {
      float ar = __shfl(alpha, (lane & 48) | (g * 4 + r), 64);
#pragma unroll
      for (int n = 0; n < 4; n++) accO[n][r] *= ar;
    }

    // pack P to bf16 pairs and publish to per-wave repack table (in-wave)
#pragma unroll
    for (int n = 0; n < 4; n++) {
      u32 lo = (u32)f2bfu(sacc[n][0]) | ((u32)f2bfu(sacc[n][1]) << 16);
      u32 hi = (u32)f2bfu(sacc[n][2]) | ((u32)f2bfu(sacc[n][3]) << 16);
      Psu[wid][lane * 9 + 2 * n]     = lo;
      Psu[wid][lane * 9 + 2 * n + 1] = hi;
    }

    // gather A-operand P fragments: pf[ks][j] = P[q=lrow][kv=ks*32+g*8+j]
    int laneA = lrow + ((g & 1) << 5);   // source g' = 2*(g&1)
    int laneB = laneA + 16;              // source g' = 2*(g&1)+1
    int nsel = g >> 1;
    __builtin_amdgcn_s_setprio(1);
#pragma unroll
    for (int ks = 0; ks < 2; ks++) {
      int nks = 2 * ks + nsel;
      union { bf16x8 v; u32 w[4]; } pk;
      pk.w[0] = Psu[wid][laneA * 9 + 2 * nks];
      pk.w[1] = Psu[wid][laneA * 9 + 2 * nks + 1];
      pk.w[2] = Psu[wid][laneB * 9 + 2 * nks];
      pk.w[3] = Psu[wid][laneB * 9 + 2 * nks + 1];
#pragma unroll
      for (int n = 0; n < 4; n++) {
        bf16x8 vf = *(const bf16x8*)&Vs[(n * 16 + lrow) * 72 + ks * 32 + g * 8];
        accO[n] = __builtin_amdgcn_mfma_f32_16x16x32_bf16(pk.v, vf,
                                                          accO[n], 0, 0, 0);
      }
    }
    __builtin_amdgcn_s_setprio(0);
  }

  // normalize + write z token-major [B][N][C] bf16; O row q'=g*4+r
#pragma unroll
  for (int r = 0; r < 4; r++) {
    float lr = __shfl(lrun, (lane & 48) | (g * 4 + r), 64);
    float inv = 1.f / lr;
    int qrow = qrow0 + g * 4 + r;
#pragma unroll
    for (int n = 0; n < 4; n++) {
      int d = n * 16 + lrow;
      Z[((size_t)(bb * SEQ + qrow)) * CH + hh * DHD + d] =
          f2bfu(accO[n][r] * inv);
    }
  }
}

// ---------------------------------------------------------------- launch
extern "C" void kernel_launch(void* const* d_in, const int* in_sizes, int n_in,
                              void* d_out, int out_size, void* d_ws,
                              size_t ws_size, hipStream_t stream) {
  (void)in_sizes; (void)n_in; (void)out_size; (void)ws_size;
  const float* x   = (const float*)d_in[0];
  const float* Wq  = (const float*)d_in[1];
  const float* bq  = (const float*)d_in[2];
  const float* Wk  = (const float*)d_in[3];
  const float* bk  = (const float*)d_in[4];
  const float* Wv  = (const float*)d_in[5];
  const float* bv  = (const float*)d_in[6];
  const float* Wo  = (const float*)d_in[7];
  const float* bo  = (const float*)d_in[8];
  const float* g1  = (const float*)d_in[9];
  const float* b1  = (const float*)d_in[10];
  const float* g2  = (const float*)d_in[11];
  const float* b2  = (const float*)d_in[12];
  const float* W1  = (const float*)d_in[13];
  const float* bf1 = (const float*)d_in[14];
  const float* W2  = (const float*)d_in[15];
  const float* bf2 = (const float*)d_in[16];

  u16* wsu  = (u16*)d_ws;
  u16* wq_t = wsu;                               // [3C][C] packed q,k,v
  u16* wo_t = wq_t + (size_t)3 * CH * CH;
  u16* w1_t = wo_t + (size_t)CH * CH;            // [FF][C]
  u16* w2_t = w1_t + (size_t)CH * FFD;           // [C][FF]
  u16* xn   = w2_t + (size_t)CH * FFD;           // [M][C]
  u16* qb   = xn + (size_t)MR * CH;              // [B*H][N][DH]; kb,vb follow
  u16* zb   = qb + (size_t)3 * MR * CH;          // [B][N][C]
  float* bres = (float*)(zb + (size_t)MR * CH);  // [M][C] fp32
  u16* hb   = qb;                                // reuse region: [M][FF]
  float* bqkv = (float*)d_out;                   // packed bias (overwritten)

  dim3 blk(256);
  k_transpose_all<<<6912, blk, 0, stream>>>(Wq, Wk, Wv, Wo, W1, W2, wsu);
  k_pack_bias<<<9, blk, 0, stream>>>(bq, bk, bv, bqkv);

  k_layernorm_bf16<<<2048, blk, 0, stream>>>(x, g1, b1, xn);
  k_gemm<EPI_QKV><<<dim3(64, 18), blk, 0, stream>>>(xn, wq_t, bqkv, nullptr,
                                                    qb, CH, 3 * CH);
  k_attn<<<dim3(16, 96), blk, 0, stream>>>(qb, qb + (size_t)MR * CH,
                                           qb + (size_t)2 * MR * CH, zb);
  k_gemm<EPI_RESID><<<dim3(64, 6), blk, 0, stream>>>(zb, wo_t, bo, x, bres,
                                                     CH, CH);
  k_layernorm_bf16<<<2048, blk, 0, stream>>>(bres, g2, b2, xn);
  k_gemm<EPI_RELU><<<dim3(64, 24), blk, 0, stream>>>(xn, w1_t, bf1, nullptr,
                                                     hb, CH, FFD);
  k_gemm<EPI_RESID><<<dim3(64, 6), blk, 0, stream>>>(hb, w2_t, bf2, bres,
                                                     (float*)d_out, FFD, CH);
}

// Round 5
// 263.494 us; speedup vs baseline: 1.2089x; 1.0455x over previous
//
#include <hip/hip_runtime.h>
#include <hip/hip_bf16.h>

// ViT encoder block: B=8, N=1024, C=768, H=12, DH=64, FF=3072, fp32 in/out,
// bf16 MFMA compute internally.
#define BDIM 8
#define SEQ  1024
#define CH   768
#define NHD  12
#define DHD  64
#define FFD  3072
#define MR   (BDIM*SEQ)   // 8192 token rows

typedef __attribute__((ext_vector_type(8))) short bf16x8;
typedef __attribute__((ext_vector_type(4))) float f32x4;
typedef unsigned int   u32;
typedef unsigned short u16;

__device__ __forceinline__ u16 f2bfu(float x) {
  __hip_bfloat16 h = __float2bfloat16(x);
  return *reinterpret_cast<u16*>(&h);
}

__device__ __forceinline__ void glds16(const void* g, void* l) {
  __builtin_amdgcn_global_load_lds(
      (const __attribute__((address_space(1))) u32*)g,
      (__attribute__((address_space(3))) u32*)l, 16, 0, 0);
}

// ---------------------------------------------------------------- transpose
// All 6 weights in one launch. W [K][Nc] fp32 -> Wt [Nc][K] bf16 in ws.
__global__ __launch_bounds__(256) void k_transpose_all(
    const float* __restrict__ Wq, const float* __restrict__ Wk,
    const float* __restrict__ Wv, const float* __restrict__ Wo,
    const float* __restrict__ W1, const float* __restrict__ W2,
    u16* __restrict__ ws) {
  __shared__ float tile[32][33];
  int b = blockIdx.x;
  int id, tb;
  if (b < 2304)      { id = b / 576; tb = b % 576; }
  else if (b < 4608) { id = 4;       tb = b - 2304; }
  else               { id = 5;       tb = b - 4608; }
  const float* src;
  u16* dst;
  int K, Nc;
  switch (id) {
    case 0: src = Wq; dst = ws;                      K = CH;  Nc = CH;  break;
    case 1: src = Wk; dst = ws + (size_t)CH*CH;      K = CH;  Nc = CH;  break;
    case 2: src = Wv; dst = ws + (size_t)2*CH*CH;    K = CH;  Nc = CH;  break;
    case 3: src = Wo; dst = ws + (size_t)3*CH*CH;    K = CH;  Nc = CH;  break;
    case 4: src = W1; dst = ws + (size_t)4*CH*CH;    K = CH;  Nc = FFD; break;
    default:src = W2; dst = ws + (size_t)4*CH*CH + (size_t)CH*FFD;
                                                     K = FFD; Nc = CH;  break;
  }
  int tilesx = Nc >> 5;
  int bx = (tb % tilesx) * 32;        // Nc dim
  int by = (tb / tilesx) * 32;        // K dim
  int tx = threadIdx.x & 31, ty = threadIdx.x >> 5;   // 32 x 8
#pragma unroll
  for (int j = 0; j < 32; j += 8)
    tile[ty + j][tx] = src[(size_t)(by + ty + j) * Nc + bx + tx];
  __syncthreads();
#pragma unroll
  for (int j = 0; j < 32; j += 8)
    dst[(size_t)(bx + ty + j) * K + by + tx] = f2bfu(tile[tx][ty + j]);
}

// ---------------------------------------------------------------- bias pack
__global__ __launch_bounds__(256) void k_pack_bias(
    const float* __restrict__ bq, const float* __restrict__ bk,
    const float* __restrict__ bv, float* __restrict__ dst) {
  int i = blockIdx.x * 256 + threadIdx.x;
  if (i < 3 * CH)
    dst[i] = i < CH ? bq[i] : (i < 2 * CH ? bk[i - CH] : bv[i - 2 * CH]);
}

// ---------------------------------------------------------------- layernorm
__global__ __launch_bounds__(256) void k_layernorm_bf16(
    const float* __restrict__ src, const float* __restrict__ gamma,
    const float* __restrict__ beta, u16* __restrict__ dst) {
  int row  = blockIdx.x * 4 + (threadIdx.x >> 6);
  int lane = threadIdx.x & 63;
  const float4* p4 = (const float4*)(src + (size_t)row * CH);
  float4 v[3];
  float s = 0.f, s2 = 0.f;
#pragma unroll
  for (int k = 0; k < 3; k++) {
    v[k] = p4[lane + k * 64];
    s  += v[k].x + v[k].y + v[k].z + v[k].w;
    s2 += v[k].x * v[k].x + v[k].y * v[k].y + v[k].z * v[k].z + v[k].w * v[k].w;
  }
#pragma unroll
  for (int m = 1; m < 64; m <<= 1) {
    s  += __shfl_xor(s,  m, 64);
    s2 += __shfl_xor(s2, m, 64);
  }
  float mean = s * (1.f / CH);
  float var  = s2 * (1.f / CH) - mean * mean;
  float rs   = rsqrtf(var + 1e-5f);
  u16* drow = dst + (size_t)row * CH;
#pragma unroll
  for (int k = 0; k < 3; k++) {
    int col = lane * 4 + k * 256;
    float4 gq = ((const float4*)gamma)[lane + k * 64];
    float4 bq = ((const float4*)beta )[lane + k * 64];
    u32 lo = (u32)f2bfu((v[k].x - mean) * rs * gq.x + bq.x) |
             ((u32)f2bfu((v[k].y - mean) * rs * gq.y + bq.y) << 16);
    u32 hi = (u32)f2bfu((v[k].z - mean) * rs * gq.z + bq.z) |
             ((u32)f2bfu((v[k].w - mean) * rs * gq.w + bq.w) << 16);
    uint2 w; w.x = lo; w.y = hi;
    *(uint2*)(drow + col) = w;
  }
}

// ---------------------------------------------------------------- GEMM
// m97 structure: TMx128 tile (TM=128 or 64), BK=32, 4 waves, dbuf LDS,
// global_load_lds. TM=64 used for N=768 GEMMs (Wo, W2) to get 768 blocks.
#define GBN 128
#define GBK 32
enum { EPI_QKV = 0, EPI_RESID = 1, EPI_RELU = 2 };

template <int EPI, int TM = 128>
__global__ __launch_bounds__(256, 2) void k_gemm(
    const u16* __restrict__ A, const u16* __restrict__ Bt,
    const float* __restrict__ bias, const float* __restrict__ resid,
    void* __restrict__ outp, int K, int Nmat) {
  __shared__ u16 As[2][TM * GBK];
  __shared__ u16 Bs[2][GBN * GBK];
  constexpr int MF = TM / 32;       // m-fragments per wave
  int tid = threadIdx.x;
  int bm = blockIdx.x, bn = blockIdx.y;
  int lane = tid & 63, wid = tid >> 6;
  int wr = (wid >> 1) * (TM / 2), wc = (wid & 1) * 64;
  int lrow = lane & 15, g = lane >> 4;

  const u16* Abase = A + (size_t)(bm * TM) * K;
  const u16* Bbase = Bt + (size_t)(bn * GBN) * K;
  int srow = tid >> 2;
  int scol = (tid & 3) * 8;

  auto stage = [&](int buf, int k0) {
#pragma unroll
    for (int r = 0; r < TM / 64; r++)
      glds16(Abase + (size_t)(srow + r * 64) * K + k0 + scol,
             &As[buf][(tid + r * 256) * 8]);
#pragma unroll
    for (int r = 0; r < 2; r++)
      glds16(Bbase + (size_t)(srow + r * 64) * K + k0 + scol,
             &Bs[buf][(tid + r * 256) * 8]);
  };

  f32x4 acc[MF][4];
#pragma unroll
  for (int m = 0; m < MF; m++)
#pragma unroll
    for (int n = 0; n < 4; n++) acc[m][n] = {0.f, 0.f, 0.f, 0.f};

  int nk = K / GBK;
  stage(0, 0);
  for (int kt = 0; kt < nk; ++kt) {
    int buf = kt & 1;
    __syncthreads();
    if (kt + 1 < nk) stage(buf ^ 1, (kt + 1) * GBK);
    bf16x8 af[MF], bfr[4];
#pragma unroll
    for (int m = 0; m < MF; m++)
      af[m] = *(const bf16x8*)&As[buf][(wr + m * 16 + lrow) * GBK + g * 8];
#pragma unroll
    for (int n = 0; n < 4; n++)
      bfr[n] = *(const bf16x8*)&Bs[buf][(wc + n * 16 + lrow) * GBK + g * 8];
#pragma unroll
    for (int m = 0; m < MF; m++)
#pragma unroll
      for (int n = 0; n < 4; n++)
        acc[m][n] = __builtin_amdgcn_mfma_f32_16x16x32_bf16(af[m], bfr[n],
                                                            acc[m][n], 0, 0, 0);
  }

  // epilogue: D row = (lane>>4)*4 + r, col = lane&15 (m89-verified mapping)
#pragma unroll
  for (int m = 0; m < MF; m++) {
    int row0 = bm * TM + wr + m * 16 + g * 4;   // multiple of 4
#pragma unroll
    for (int n = 0; n < 4; n++) {
      int col = bn * GBN + wc + n * 16 + lrow;
      float bval = bias[col];
      if constexpr (EPI == EPI_QKV) {
        // col tile lies in one sel (768 = 6*128)
        int sel = col / CH;
        int c = col - sel * CH;
        int h = c >> 6, d = c & 63;
        int bb = row0 >> 10, nn0 = row0 & (SEQ - 1);
        if (sel == 2) {
          // V stored TRANSPOSED per head: [B*H][DH][N]; 4 consecutive n -> 8B
          union { uint2 u; u16 h4[4]; } pk;
#pragma unroll
          for (int r = 0; r < 4; r++) pk.h4[r] = f2bfu(acc[m][n][r] + bval);
          *(uint2*)&((u16*)outp)[(size_t)2 * MR * CH +
                                 (((size_t)(bb * NHD + h)) * DHD + d) * SEQ +
                                 nn0] = pk.u;
        } else {
#pragma unroll
          for (int r = 0; r < 4; r++)
            ((u16*)outp)[(size_t)sel * MR * CH +
                         (((size_t)(bb * NHD + h)) * SEQ + nn0 + r) * DHD + d] =
                f2bfu(acc[m][n][r] + bval);
        }
      } else if constexpr (EPI == EPI_RESID) {
#pragma unroll
        for (int r = 0; r < 4; r++) {
          size_t idx = (size_t)(row0 + r) * Nmat + col;
          ((float*)outp)[idx] = acc[m][n][r] + bval + resid[idx];
        }
      } else {  // RELU -> bf16 row-major
#pragma unroll
        for (int r = 0; r < 4; r++) {
          float val = acc[m][n][r] + bval;
          ((u16*)outp)[(size_t)(row0 + r) * Nmat + col] =
              f2bfu(val > 0.f ? val : 0.f);
        }
      }
    }
  }
}

// ---------------------------------------------------------------- attention
// flash-style, SWAPPED QK^T (S^T = K Q^T): lane owns q-row = lane&15;
// softmax = in-lane tree + 2 shfl_xor, defer-max rescale (T13, THR=8).
// K [64kv][64d] and V^T [64d][64kv] tiles staged DIRECT to LDS via
// global_load_lds with pre-swizzled global source (m173); reads XOR-swizzled
// b128 (T2, involution both sides). Double-buffered, ONE barrier per tile.
// grid 1536 blocks, bijective XCD swizzle.
__global__ __launch_bounds__(256, 2) void k_attn(
    const u16* __restrict__ Q, const u16* __restrict__ Kk,
    const u16* __restrict__ Vt, u16* __restrict__ Z) {
  __shared__ u16 Ks[2][64 * 64];
  __shared__ u16 Vs[2][64 * 64];     // V^T tile: [d][kv]
  __shared__ u32 Psu[4][64 * 9];     // per-wave P repack: [lane][2n+hi]
  int tid = threadIdx.x, lane = tid & 63, wid = tid >> 6;
  int lrow = lane & 15, g = lane >> 4;
  // bijective XCD swizzle: 1536 blocks = 8 XCD x 192
  int id  = blockIdx.y * 16 + blockIdx.x;
  int nid = (id & 7) * 192 + (id >> 3);
  int qtile = (nid & 15) * 64;
  int bh = nid >> 4;
  size_t base = (size_t)bh * SEQ * DHD;
  int bb = bh / NHD, hh = bh % NHD;
  int qrow0 = qtile + wid * 16;

  // Q as B-operand fragments (col = q = lrow), held for the whole kernel
  bf16x8 qf[2];
#pragma unroll
  for (int ks = 0; ks < 2; ks++)
    qf[ks] = *(const bf16x8*)(Q + base + (size_t)(qrow0 + lrow) * DHD +
                              ks * 32 + g * 8);

  f32x4 accO[4];                    // O[q=g*4+r][d=n*16+lrow]
  float mrun = -1e30f, lrun = 0.f;  // stats for q = lrow (replicated over g)
#pragma unroll
  for (int n = 0; n < 4; n++) accO[n] = {0.f, 0.f, 0.f, 0.f};

  // staging geometry: thread -> (row = tid>>3 [+32], byte col (tid&7)*16);
  // global col pre-swizzled so LDS stays linear; reads apply the same XOR.
  int srow  = tid >> 3;                                    // 0..31
  int swz   = (((tid & 7) * 16) ^ ((srow & 7) << 4)) >> 1; // u16 col; same for row+32
  const u16* kg0 = Kk + base + (size_t)srow * DHD + swz;
  const u16* vg0 = Vt + base + (size_t)srow * SEQ + swz;

  auto stageKV = [&](int buf, int t) {
    int kv0 = t * 64;
    const u16* kg = kg0 + (size_t)kv0 * DHD;
    glds16(kg,                    &Ks[buf][tid * 8]);
    glds16(kg + 32 * DHD,         &Ks[buf][2048 + tid * 8]);
    const u16* vg = vg0 + kv0;
    glds16(vg,                    &Vs[buf][tid * 8]);
    glds16(vg + 32 * SEQ,         &Vs[buf][2048 + tid * 8]);
  };

  // read-side swizzled u16 col offsets (row parity = lrow&7)
  int rc0 = ((g * 16)      ^ ((lrow & 7) << 4)) >> 1;   // ks=0
  int rc1 = ((64 + g * 16) ^ ((lrow & 7) << 4)) >> 1;   // ks=1

  stageKV(0, 0);
  for (int t = 0; t < 16; ++t) {
    int buf = t & 1;
    __syncthreads();                 // drains glds (vmcnt0) + protects dbuf
    if (t + 1 < 16) stageKV(buf ^ 1, t + 1);

    // S^T = K Q^T : sacc[n][r] = S[kv = n*16 + g*4 + r][q = lrow]
    f32x4 sacc[4];
    __builtin_amdgcn_s_setprio(1);
#pragma unroll
    for (int n = 0; n < 4; n++) {
      bf16x8 kf0 = *(const bf16x8*)&Ks[buf][(n * 16 + lrow) * 64 + rc0];
      bf16x8 kf1 = *(const bf16x8*)&Ks[buf][(n * 16 + lrow) * 64 + rc1];
      sacc[n] = {0.f, 0.f, 0.f, 0.f};
      sacc[n] = __builtin_amdgcn_mfma_f32_16x16x32_bf16(kf0, qf[0], sacc[n], 0, 0, 0);
      sacc[n] = __builtin_amdgcn_mfma_f32_16x16x32_bf16(kf1, qf[1], sacc[n], 0, 0, 0);
    }
    __builtin_amdgcn_s_setprio(0);

    // online softmax for q = lrow: in-lane tree + 2 shfls
    float mx = fmaxf(fmaxf(fmaxf(sacc[0][0], sacc[0][1]),
                           fmaxf(sacc[0][2], sacc[0][3])),
                     fmaxf(fmaxf(sacc[1][0], sacc[1][1]),
                           fmaxf(sacc[1][2], sacc[1][3])));
    mx = fmaxf(mx, fmaxf(fmaxf(fmaxf(sacc[2][0], sacc[2][1]),
                               fmaxf(sacc[2][2], sacc[2][3])),
                         fmaxf(fmaxf(sacc[3][0], sacc[3][1]),
                               fmaxf(sacc[3][2], sacc[3][3]))));
    mx *= 0.125f;
    mx = fmaxf(mx, __shfl_xor(mx, 16, 64));
    mx = fmaxf(mx, __shfl_xor(mx, 32, 64));

    if (__all(mx <= mrun + 8.f)) {
      // deferred: keep old max, no O-rescale (P bounded by e^8)
      float psum = 0.f;
#pragma unroll
      for (int n = 0; n < 4; n++)
#pragma unroll
        for (int r = 0; r < 4; r++) {
          float p = __expf(sacc[n][r] * 0.125f - mrun);
          sacc[n][r] = p;
          psum += p;
        }
      psum += __shfl_xor(psum, 16, 64);
      psum += __shfl_xor(psum, 32, 64);
      lrun += psum;
    } else {
      float mnew = fmaxf(mrun, mx);
      float alpha = __expf(mrun - mnew);
      float psum = 0.f;
#pragma unroll
      for (int n = 0; n < 4; n++)
#pragma unroll
        for (int r = 0; r < 4; r++) {
          float p = __expf(sacc[n][r] * 0.125f - mnew);
          sacc[n][r] = p;
          psum += p;
        }
      psum += __shfl_xor(psum, 16, 64);
      psum += __shfl_xor(psum, 32, 64);
      lrun = lrun * alpha + psum;
      mrun = mnew;
      // rescale O: row q' = g*4+r needs alpha of lane (lane&48)|(g*4+r)
#pragma unroll
      for (int r = 0; r < 4; r++) {
        float ar = __shfl(alpha, (lane & 48) | (g * 4 + r), 64);
#pragma unroll
        for (int n = 0; n < 4; n++) accO[n][r] *= ar;
      }
    }

    // pack P to bf16 pairs and publish to per-wave repack table (in-wave)
#pragma unroll
    for (int n = 0; n < 4; n++) {
      u32 lo = (u32)f2bfu(sacc[n][0]) | ((u32)f2bfu(sacc[n][1]) << 16);
      u32 hi = (u32)f2bfu(sacc[n][2]) | ((u32)f2bfu(sacc[n][3]) << 16);
      Psu[wid][lane * 9 + 2 * n]     = lo;
      Psu[wid][lane * 9 + 2 * n + 1] = hi;
    }

    // gather A-operand P fragments + PV
    int laneA = lrow + ((g & 1) << 5);   // source g' = 2*(g&1)
    int laneB = laneA + 16;              // source g' = 2*(g&1)+1
    int nsel = g >> 1;
    __builtin_amdgcn_s_setprio(1);
#pragma unroll
    for (int ks = 0; ks < 2; ks++) {
      int nks = 2 * ks + nsel;
      union { bf16x8 v; u32 w[4]; } pk;
      pk.w[0] = Psu[wid][laneA * 9 + 2 * nks];
      pk.w[1] = Psu[wid][laneA * 9 + 2 * nks + 1];
      pk.w[2] = Psu[wid][laneB * 9 + 2 * nks];
      pk.w[3] = Psu[wid][laneB * 9 + 2 * nks + 1];
      int rc = ks ? rc1 : rc0;
#pragma unroll
      for (int n = 0; n < 4; n++) {
        bf16x8 vf = *(const bf16x8*)&Vs[buf][(n * 16 + lrow) * 64 + rc];
        accO[n] = __builtin_amdgcn_mfma_f32_16x16x32_bf16(pk.v, vf,
                                                          accO[n], 0, 0, 0);
      }
    }
    __builtin_amdgcn_s_setprio(0);
  }

  // normalize + write z token-major [B][N][C] bf16; O row q'=g*4+r
#pragma unroll
  for (int r = 0; r < 4; r++) {
    float lr = __shfl(lrun, (lane & 48) | (g * 4 + r), 64);
    float inv = 1.f / lr;
    int qrow = qrow0 + g * 4 + r;
#pragma unroll
    for (int n = 0; n < 4; n++) {
      int d = n * 16 + lrow;
      Z[((size_t)(bb * SEQ + qrow)) * CH + hh * DHD + d] =
          f2bfu(accO[n][r] * inv);
    }
  }
}

// ---------------------------------------------------------------- launch
extern "C" void kernel_launch(void* const* d_in, const int* in_sizes, int n_in,
                              void* d_out, int out_size, void* d_ws,
                              size_t ws_size, hipStream_t stream) {
  (void)in_sizes; (void)n_in; (void)out_size; (void)ws_size;
  const float* x   = (const float*)d_in[0];
  const float* Wq  = (const float*)d_in[1];
  const float* bq  = (const float*)d_in[2];
  const float* Wk  = (const float*)d_in[3];
  const float* bk  = (const float*)d_in[4];
  const float* Wv  = (const float*)d_in[5];
  const float* bv  = (const float*)d_in[6];
  const float* Wo  = (const float*)d_in[7];
  const float* bo  = (const float*)d_in[8];
  const float* g1  = (const float*)d_in[9];
  const float* b1  = (const float*)d_in[10];
  const float* g2  = (const float*)d_in[11];
  const float* b2  = (const float*)d_in[12];
  const float* W1  = (const float*)d_in[13];
  const float* bf1 = (const float*)d_in[14];
  const float* W2  = (const float*)d_in[15];
  const float* bf2 = (const float*)d_in[16];

  u16* wsu  = (u16*)d_ws;
  u16* wq_t = wsu;                               // [3C][C] packed q,k,v
  u16* wo_t = wq_t + (size_t)3 * CH * CH;
  u16* w1_t = wo_t + (size_t)CH * CH;            // [FF][C]
  u16* w2_t = w1_t + (size_t)CH * FFD;           // [C][FF]
  u16* xn   = w2_t + (size_t)CH * FFD;           // [M][C]
  u16* qb   = xn + (size_t)MR * CH;              // q,k: [B*H][N][DH]; v: [B*H][DH][N]
  u16* zb   = qb + (size_t)3 * MR * CH;          // [B][N][C]
  float* bres = (float*)(zb + (size_t)MR * CH);  // [M][C] fp32
  u16* hb   = qb;                                // reuse region: [M][FF]
  float* bqkv = (float*)d_out;                   // packed bias (overwritten)

  dim3 blk(256);
  k_transpose_all<<<6912, blk, 0, stream>>>(Wq, Wk, Wv, Wo, W1, W2, wsu);
  k_pack_bias<<<9, blk, 0, stream>>>(bq, bk, bv, bqkv);

  k_layernorm_bf16<<<2048, blk, 0, stream>>>(x, g1, b1, xn);
  k_gemm<EPI_QKV><<<dim3(64, 18), blk, 0, stream>>>(xn, wq_t, bqkv, nullptr,
                                                    qb, CH, 3 * CH);
  k_attn<<<dim3(16, 96), blk, 0, stream>>>(qb, qb + (size_t)MR * CH,
                                           qb + (size_t)2 * MR * CH, zb);
  k_gemm<EPI_RESID, 64><<<dim3(128, 6), blk, 0, stream>>>(zb, wo_t, bo, x,
                                                          bres, CH, CH);
  k_layernorm_bf16<<<2048, blk, 0, stream>>>(bres, g2, b2, xn);
  k_gemm<EPI_RELU><<<dim3(64, 24), blk, 0, stream>>>(xn, w1_t, bf1, nullptr,
                                                     hb, CH, FFD);
  k_gemm<EPI_RESID, 64><<<dim3(128, 6), blk, 0, stream>>>(hb, w2_t, bf2, bres,
                                                          (float*)d_out, FFD, CH);
}